// Round 9
// baseline (226.618 us; speedup 1.0000x reference)
//
#include <hip/hip_runtime.h>
#include <hip/hip_bf16.h>

typedef __attribute__((ext_vector_type(8))) short short8;
typedef __attribute__((ext_vector_type(4))) short s4v;
typedef __attribute__((ext_vector_type(4))) float floatx4;

__device__ inline floatx4 mfma_bf16(short8 a, short8 b, floatx4 c) {
  return __builtin_amdgcn_mfma_f32_16x16x32_bf16(a, b, c, 0, 0, 0);
}
__device__ inline float exp2_fast(float x) { return __builtin_amdgcn_exp2f(x); }

__device__ inline short bf16s(float f) {
  __hip_bfloat16 h = __float2bfloat16(f);
  return *reinterpret_cast<short*>(&h);
}
__device__ inline float sbf16(short s) {
  return __bfloat162float(*reinterpret_cast<__hip_bfloat16*>(&s));
}

// async global->LDS, 16B per lane. LDS dest must be wave-uniform base + lane*16.
__device__ inline void gld16(__hip_bfloat16* lds, const __hip_bfloat16* g) {
  __builtin_amdgcn_global_load_lds(
      (const __attribute__((address_space(1))) void*)g,
      (__attribute__((address_space(3))) void*)lds, 16, 0, 0);
}

// ---------------------------------------------------------------- fused cvt
__global__ __launch_bounds__(256) void cvt_all(
    const float* __restrict__ x, const float* __restrict__ wqkv,
    const float* __restrict__ wout, __hip_bfloat16* __restrict__ xb,
    __hip_bfloat16* __restrict__ wqkvb, __hip_bfloat16* __restrict__ wob) {
  const int n1 = 4194304, n2 = 3145728;  // n3 = 1048576
  int i = (blockIdx.x * 256 + threadIdx.x) * 8;
  const float* src;
  __hip_bfloat16* dst;
  int off;
  if (i < n1) { src = x; dst = xb; off = i; }
  else if (i < n1 + n2) { src = wqkv; dst = wqkvb; off = i - n1; }
  else { src = wout; dst = wob; off = i - n1 - n2; }
  float4 a = *reinterpret_cast<const float4*>(src + off);
  float4 b = *reinterpret_cast<const float4*>(src + off + 4);
  __hip_bfloat16 t[8];
  t[0] = __float2bfloat16(a.x); t[1] = __float2bfloat16(a.y);
  t[2] = __float2bfloat16(a.z); t[3] = __float2bfloat16(a.w);
  t[4] = __float2bfloat16(b.x); t[5] = __float2bfloat16(b.y);
  t[6] = __float2bfloat16(b.z); t[7] = __float2bfloat16(b.w);
  *reinterpret_cast<short8*>(dst + off) = *reinterpret_cast<short8*>(t);
}

// ================================================================ shared GEMM bits
__device__ inline void stage_half(__hip_bfloat16* lds, const __hip_bfloat16* g,
                                  int K, int tid) {
#pragma unroll
  for (int it = 0; it < 2; ++it) {
    int idx = it * 512 + tid;
    int row = idx >> 3, col = ((idx & 7) ^ (row & 7)) * 8;
    gld16(lds + idx * 8, g + (size_t)row * K + col);
  }
}
// 64-row half-size stage (8KB): one gld16 per thread
__device__ inline void stage_q(__hip_bfloat16* lds, const __hip_bfloat16* g,
                               int K, int tid) {
  int row = tid >> 3, col = ((tid & 7) ^ (row & 7)) * 8;
  gld16(lds + tid * 8, g + (size_t)row * K + col);
}

#define VMW(N) asm volatile("s_waitcnt vmcnt(" #N ")" ::: "memory")
#define BAR __builtin_amdgcn_s_barrier()

// ---------------------------------------------------------------- GEMM 256x256 v6b (QKV)
// READ-AHEAD schedule: LDS reads issued one phase before their MFMA so the
// ~857cy LDS service (8 waves x 12 reads) hides under MFMA+BAR.
// Phase order (0,0),(1,0),(1,1),(0,1); af0 read ONCE (used P0+P3); ping-pong
// af0A/af0B via 2-tile unroll (static names). Peak live frags 96 (af1
// overlaps the dead af0X slot) -> ~125 VGPR, acc in 128 AGPRs.
// Reads per phase: P0: af1(8); P1: bf1(4); P2: 0; P3: af0'(8)+bf0'(4).
// Stages (tile t+2 into cb): P1: A0+B0, P2: A1, P3: B1.
// Steady waits (verified by per-wave queue simulation; 8 loads/tile):
//   end-P0 VMW(8):  forces B1(t)      [issued P3(t-2), 5-phase slack]
//   end-P2 VMW(10): forces A0B0(t+1)  [issued P1(t-1), 5-phase slack]
//   end-P3 VMW(10): forces A1(t+1)    [issued P2(t-1), 5-phase slack]
// Peel pair {NT-2,NT-1}: entering queue = 10 {B1,A1,A0B0 of NT-1; B1(NT-2)};
//   NT-2 -> (8,4,2); NT-1 -> VMW(0) at end-P0. Requires NT even, >= 4.
// DMA-vs-read per slot (all safe, >=1 barrier between consumption and DMA):
//   SA[cb][0]: read P3(t-1)->consumed P0(t); DMA P1(t).
//   SA[cb][1]: read P0(t)->consumed P1(t); DMA P2(t).
//   SB[cb][0]: read P3(t-1)->consumed P0(t); DMA P1(t).
//   SB[cb][1]: read P1(t)->consumed P2(t); DMA P3(t).
#define LDA8(dst, BUF, MH)                                                     \
  do {                                                                         \
    _Pragma("unroll") for (int mf = 0; mf < 4; ++mf) {                         \
      int rh = wm * 64 + mf * 16 + l15;                                        \
      _Pragma("unroll") for (int ks = 0; ks < 2; ++ks)                         \
          dst[mf][ks] = *reinterpret_cast<const short8*>(                      \
              &SA[BUF][MH][rh * 64 + (((ks * 4 + quad) ^ (rh & 7)) * 8)]);     \
    }                                                                          \
  } while (0)
#define LDB4(dst, BUF, NH)                                                     \
  do {                                                                         \
    _Pragma("unroll") for (int nf = 0; nf < 2; ++nf) {                         \
      int rh = wn * 32 + nf * 16 + l15;                                        \
      _Pragma("unroll") for (int ks = 0; ks < 2; ++ks)                         \
          dst[nf][ks] = *reinterpret_cast<const short8*>(                      \
              &SB[BUF][NH][rh * 64 + (((ks * 4 + quad) ^ (rh & 7)) * 8)]);     \
    }                                                                          \
  } while (0)
#define MM16(MH, NH, AF, BF)                                                   \
  do {                                                                         \
    _Pragma("unroll") for (int mf = 0; mf < 4; ++mf)                           \
        _Pragma("unroll") for (int nf = 0; nf < 2; ++nf) {                     \
      acc[MH][NH][mf][nf] = mfma_bf16(AF[mf][0], BF[nf][0], acc[MH][NH][mf][nf]); \
      acc[MH][NH][mf][nf] = mfma_bf16(AF[mf][1], BF[nf][1], acc[MH][NH][mf][nf]); \
    }                                                                          \
  } while (0)
// One K-tile: AF0C = this tile's A0 frags (preloaded last P3), AF0N = next's.
#define TILE6(CB, NB, AF0C, AF0N, STG1, STG2, STG3, W0, W2, W3)                \
  do {                                                                         \
    LDA8(af1, CB, 1);                                                          \
    __builtin_amdgcn_s_setprio(1);                                             \
    MM16(0, 0, AF0C, bf0);                                                     \
    __builtin_amdgcn_s_setprio(0);                                             \
    W0; BAR;                                                                   \
    LDB4(bf1, CB, 1);                                                          \
    STG1;                                                                      \
    __builtin_amdgcn_s_setprio(1);                                             \
    MM16(1, 0, af1, bf0);                                                      \
    __builtin_amdgcn_s_setprio(0);                                             \
    BAR;                                                                       \
    STG2;                                                                      \
    __builtin_amdgcn_s_setprio(1);                                             \
    MM16(1, 1, af1, bf1);                                                      \
    __builtin_amdgcn_s_setprio(0);                                             \
    W2; BAR;                                                                   \
    LDA8(AF0N, NB, 0);                                                         \
    LDB4(bf0, NB, 0);                                                          \
    STG3;                                                                      \
    __builtin_amdgcn_s_setprio(1);                                             \
    MM16(0, 1, AF0C, bf1);                                                     \
    __builtin_amdgcn_s_setprio(0);                                             \
    W3; BAR;                                                                   \
  } while (0)

template<bool OUT_BF16>
__global__ __launch_bounds__(512, 2) void gemm_256(
    const __hip_bfloat16* __restrict__ A, const __hip_bfloat16* __restrict__ Bt,
    const float* __restrict__ bias, void* __restrict__ Cout,
    int M, int N, int K) {
  __shared__ __align__(16) __hip_bfloat16 SA[2][2][128 * 64];
  __shared__ __align__(16) __hip_bfloat16 SB[2][2][128 * 64];
  const int tid = threadIdx.x;
  const int lane = tid & 63, quad = (lane >> 4), l15 = lane & 15;
  const int wave = tid >> 6;
  const int wm = wave >> 2, wn = wave & 3;

  // bijective XCD swizzle (nwg % 8 == 0 for our shapes)
  const int nbx = gridDim.x;
  int bid = blockIdx.y * nbx + blockIdx.x;
  const int nwg = nbx * gridDim.y;
  if ((nwg & 7) == 0) bid = (bid & 7) * (nwg >> 3) + (bid >> 3);
  const int bx = bid % nbx, by = bid / nbx;
  const int m0 = by * 256, n0 = bx * 256;

  const __hip_bfloat16* Abase = A + (size_t)m0 * K;
  const __hip_bfloat16* Bbase = Bt + (size_t)n0 * K;
  const int NT = K >> 6;  // requires NT even, >= 4

  floatx4 acc[2][2][4][2];
#pragma unroll
  for (int a = 0; a < 2; ++a)
#pragma unroll
    for (int b = 0; b < 2; ++b)
#pragma unroll
      for (int c = 0; c < 4; ++c)
#pragma unroll
        for (int d = 0; d < 2; ++d) acc[a][b][c][d] = (floatx4){0.f, 0.f, 0.f, 0.f};

  short8 af0A[4][2], af0B[4][2];  // A0 frags ping-pong (even/odd tiles)
  short8 af1[4][2];               // A1 frags (live P0..P2)
  short8 bf0[2][2], bf1[2][2];    // B frags (bf0 live P3(prev)..P1; bf1 P1..P3)

  // ---- prologue: tiles 0,1 in steady per-tile order {A0,B0,A1,B1}
  stage_half(&SA[0][0][0], Abase, K, tid);
  stage_half(&SB[0][0][0], Bbase, K, tid);
  stage_half(&SA[0][1][0], Abase + (size_t)128 * K, K, tid);
  stage_half(&SB[0][1][0], Bbase + (size_t)128 * K, K, tid);
  stage_half(&SA[1][0][0], Abase + 64, K, tid);
  stage_half(&SB[1][0][0], Bbase + 64, K, tid);
  stage_half(&SA[1][1][0], Abase + (size_t)128 * K + 64, K, tid);
  stage_half(&SB[1][1][0], Bbase + (size_t)128 * K + 64, K, tid);
  VMW(12);  // forces A0(0),B0(0)
  BAR;
  LDA8(af0A, 0, 0);
  LDB4(bf0, 0, 0);
  VMW(10);  // forces A1(0) (for P0's af1 read; published by next BAR)
  BAR;

  // ---- steady: 2-tile unrolled, stages tiles t+2, t+3; steady waits on BOTH
  // tiles of every pair (per-wave queue simulation; tail handled by the peel).
  for (int t = 0; t <= NT - 4; t += 2) {
    const size_t k2 = (size_t)(t + 2) * 64, k3 = (size_t)(t + 3) * 64;
    TILE6(0, 1, af0A, af0B,
          { stage_half(&SA[0][0][0], Abase + k2, K, tid);
            stage_half(&SB[0][0][0], Bbase + k2, K, tid); },
          stage_half(&SA[0][1][0], Abase + (size_t)128 * K + k2, K, tid),
          stage_half(&SB[0][1][0], Bbase + (size_t)128 * K + k2, K, tid),
          VMW(8), VMW(10), VMW(10));
    TILE6(1, 0, af0B, af0A,
          { stage_half(&SA[1][0][0], Abase + k3, K, tid);
            stage_half(&SB[1][0][0], Bbase + k3, K, tid); },
          stage_half(&SA[1][1][0], Abase + (size_t)128 * K + k3, K, tid),
          stage_half(&SB[1][1][0], Bbase + (size_t)128 * K + k3, K, tid),
          VMW(8), VMW(10), VMW(10));
  }
  {  // ---- t = NT-2 (even, cb=0): no stages, draining waits (8,4,2)
    TILE6(0, 1, af0A, af0B, (void)0, (void)0, (void)0, VMW(8), VMW(4), VMW(2));
  }
  {  // ---- t = NT-1 (odd, cb=1): final tile
    LDA8(af1, 1, 1);
    __builtin_amdgcn_s_setprio(1);
    MM16(0, 0, af0B, bf0);
    __builtin_amdgcn_s_setprio(0);
    VMW(0);
    BAR;
    LDB4(bf1, 1, 1);
    __builtin_amdgcn_s_setprio(1);
    MM16(1, 0, af1, bf0);
    __builtin_amdgcn_s_setprio(0);
    BAR;
    __builtin_amdgcn_s_setprio(1);
    MM16(1, 1, af1, bf1);
    MM16(0, 1, af0B, bf1);
    __builtin_amdgcn_s_setprio(0);
  }

  // ---- epilogue
#pragma unroll
  for (int nh = 0; nh < 2; ++nh)
#pragma unroll
    for (int nf = 0; nf < 2; ++nf) {
      int gn = n0 + nh * 128 + wn * 32 + nf * 16 + l15;
      float bv = bias[gn];
#pragma unroll
      for (int mh = 0; mh < 2; ++mh)
#pragma unroll
        for (int mf = 0; mf < 4; ++mf)
#pragma unroll
          for (int rg = 0; rg < 4; ++rg) {
            int gm = m0 + mh * 128 + wm * 64 + mf * 16 + quad * 4 + rg;
            float v = acc[mh][nh][mf][nf][rg] + bv;
            if (OUT_BF16)
              ((__hip_bfloat16*)Cout)[(size_t)gm * N + gn] = __float2bfloat16(v);
            else
              ((float*)Cout)[(size_t)gm * N + gn] = v;
          }
    }
}

// ---------------------------------------------------------------- GEMM 256x64 (out-proj) v3
// Triple-buffered, ONE phase per K-tile, ONE barrier per phase. (unchanged)
__global__ __launch_bounds__(512, 2) void gemm_n64(
    const __hip_bfloat16* __restrict__ A, const __hip_bfloat16* __restrict__ Bt,
    const float* __restrict__ bias, float* __restrict__ Cout,
    int M, int N, int K) {
  __shared__ __align__(16) __hip_bfloat16 SA[3][2][128 * 64];
  __shared__ __align__(16) __hip_bfloat16 SB[3][64 * 64];
  const int tid = threadIdx.x;
  const int lane = tid & 63, quad = (lane >> 4), l15 = lane & 15;
  const int wave = tid >> 6;
  const int wm = wave >> 2, wn = wave & 3;

  const int nbx = gridDim.x;
  int bid = blockIdx.y * nbx + blockIdx.x;
  const int nwg = nbx * gridDim.y;
  if ((nwg & 7) == 0) bid = (bid & 7) * (nwg >> 3) + (bid >> 3);
  const int bx = bid % nbx, by = bid / nbx;
  const int m0 = by * 256, n0 = bx * 64;

  const __hip_bfloat16* Abase = A + (size_t)m0 * K;
  const __hip_bfloat16* Bbase = Bt + (size_t)n0 * K;
  const int NT = K >> 6;  // requires NT >= 3

  floatx4 acc[2][4];
#pragma unroll
  for (int a = 0; a < 2; ++a)
#pragma unroll
    for (int c = 0; c < 4; ++c) acc[a][c] = (floatx4){0.f, 0.f, 0.f, 0.f};

  short8 af0[4][2], af1[4][2];  // A frags mh0 / mh1
  short8 bf[2];                 // B frags (wave's 16 cols)

#define N64_LDA(dst, BUF, MH)                                                  \
  do {                                                                         \
    _Pragma("unroll") for (int mf = 0; mf < 4; ++mf) {                         \
      int rh = wm * 64 + mf * 16 + l15;                                        \
      _Pragma("unroll") for (int ks = 0; ks < 2; ++ks)                         \
          dst[mf][ks] = *reinterpret_cast<const short8*>(                      \
              &SA[BUF][MH][rh * 64 + (((ks * 4 + quad) ^ (rh & 7)) * 8)]);     \
    }                                                                          \
  } while (0)
#define N64_LDB(BUF)                                                           \
  do {                                                                         \
    int rh = wn * 16 + l15;                                                    \
    _Pragma("unroll") for (int ks = 0; ks < 2; ++ks)                           \
        bf[ks] = *reinterpret_cast<const short8*>(                             \
            &SB[BUF][rh * 64 + (((ks * 4 + quad) ^ (rh & 7)) * 8)]);           \
  } while (0)
#define N64_MM(MH, AF)                                                         \
  do {                                                                         \
    _Pragma("unroll") for (int mf = 0; mf < 4; ++mf) {                         \
      acc[MH][mf] = mfma_bf16(AF[mf][0], bf[0], acc[MH][mf]);                  \
      acc[MH][mf] = mfma_bf16(AF[mf][1], bf[1], acc[MH][mf]);                  \
    }                                                                          \
  } while (0)

  // ---- prologue: t0 -> buf0, t1 -> buf1 (order per tile: A0,A1,B)
  stage_half(&SA[0][0][0], Abase, K, tid);
  stage_half(&SA[0][1][0], Abase + (size_t)128 * K, K, tid);
  stage_q(&SB[0][0], Bbase, K, tid);
  stage_half(&SA[1][0][0], Abase + 64, K, tid);
  stage_half(&SA[1][1][0], Abase + (size_t)128 * K + 64, K, tid);
  stage_q(&SB[1][0], Bbase + 64, K, tid);
  VMW(5);  // forces tile 0
  BAR;

  int cb = 0, sb = 2;
  for (int t = 0; t <= NT - 3; ++t) {
    const size_t k2 = (size_t)(t + 2) * 64;
    N64_LDA(af0, cb, 0);
    N64_LDA(af1, cb, 1);
    N64_LDB(cb);
    stage_half(&SA[sb][0][0], Abase + k2, K, tid);
    stage_half(&SA[sb][1][0], Abase + (size_t)128 * K + k2, K, tid);
    stage_q(&SB[sb][0], Bbase + k2, K, tid);
    __builtin_amdgcn_s_setprio(1);
    N64_MM(0, af0);
    N64_MM(1, af1);
    __builtin_amdgcn_s_setprio(0);
    VMW(5);  // forces tile t+1 (staged at phase t-1)
    BAR;
    cb = (cb == 2) ? 0 : cb + 1;
    sb = (sb == 2) ? 0 : sb + 1;
  }
  {  // ---- t = NT-2: no stage, drain tile NT-1
    N64_LDA(af0, cb, 0);
    N64_LDA(af1, cb, 1);
    N64_LDB(cb);
    __builtin_amdgcn_s_setprio(1);
    N64_MM(0, af0);
    N64_MM(1, af1);
    __builtin_amdgcn_s_setprio(0);
    VMW(0);
    BAR;
    cb = (cb == 2) ? 0 : cb + 1;
  }
  {  // ---- t = NT-1
    N64_LDA(af0, cb, 0);
    N64_LDA(af1, cb, 1);
    N64_LDB(cb);
    __builtin_amdgcn_s_setprio(1);
    N64_MM(0, af0);
    N64_MM(1, af1);
    __builtin_amdgcn_s_setprio(0);
  }

  // ---- epilogue (fp32 out)
  {
    int gn = n0 + wn * 16 + l15;
    float bv = bias[gn];
#pragma unroll
    for (int mh = 0; mh < 2; ++mh)
#pragma unroll
      for (int mf = 0; mf < 4; ++mf)
#pragma unroll
        for (int rg = 0; rg < 4; ++rg) {
          int gm = m0 + mh * 128 + wm * 64 + mf * 16 + quad * 4 + rg;
          Cout[(size_t)gm * N + gn] = acc[mh][mf][rg] + bv;
        }
  }
#undef N64_LDA
#undef N64_LDB
#undef N64_MM
}

// ---------------------------------------------------------------- flash attn v10
// ((256,4): grid is exactly 4 blocks/CU. v10 structure unchanged.)
__global__ __launch_bounds__(256, 4) void flash_attn(
    const __hip_bfloat16* __restrict__ qkv, __hip_bfloat16* __restrict__ out) {
  const int S = 2048, QKV = 3072;
  const int bx = blockIdx.x;
  const int g = (blockIdx.y >> 3) + 2 * blockIdx.z;
  int qt;
  if (g == 0)      qt = bx;
  else if (g == 1) qt = 31 - bx;
  else if (g == 2) qt = (bx + 8) & 31;
  else             qt = (23 - bx) & 31;
  const int h = blockIdx.y, b = blockIdx.z;
  const int q0 = qt * 64;
  __shared__ __align__(16) short Ps[2][64 * 64];  // P double-buffer; Ps[1] stages Q
  const int tid = threadIdx.x;
  const int wave = tid >> 6, lane = tid & 63, quad = lane >> 4, l15 = lane & 15;
  const int rx = l15 & 7;
  const __hip_bfloat16* base = qkv + (size_t)b * S * QKV;
  const float c2 = 0.18033688011112042f;  // (1/sqrt(64)) * log2(e)
  const floatx4 zero4 = {0.f, 0.f, 0.f, 0.f};
  const int krow = 16 * wave + l15;  // wave's K-row (QK) and d-column (PV)

  const __hip_bfloat16* kbase = base + 1024 + h * 64;  // K plane
  const __hip_bfloat16* vbase = base + 2048 + h * 64;  // V plane

  // ---- prologue: Q (scaled) -> Ps[1]; K_0 frags -> regs
  for (int it = 0; it < 2; ++it) {
    int v = tid + it * 256;
    int row = v >> 3, cb = v & 7;
    int colp = (cb ^ (row & 7)) * 8;
    short8 qv = *reinterpret_cast<const short8*>(
        base + (size_t)(q0 + row) * QKV + h * 64 + cb * 8);
    short qs[8];
    for (int e = 0; e < 8; ++e) qs[e] = bf16s(sbf16(qv[e]) * c2);
    *reinterpret_cast<short8*>(&Ps[1][row * 64 + colp]) = *reinterpret_cast<short8*>(qs);
  }
  short8 kA0 = *reinterpret_cast<const short8*>(
      kbase + (size_t)krow * QKV + quad * 8);
  short8 kA1 = *reinterpret_cast<const short8*>(
      kbase + (size_t)krow * QKV + 32 + quad * 8);
  __syncthreads();  // Q visible

  short8 aq[4][2];  // Q B-frags: all 64 q rows x both d-halves
  for (int t4 = 0; t4 < 4; ++t4)
    for (int s = 0; s < 2; ++s)
      aq[t4][s] = *reinterpret_cast<const short8*>(
          &Ps[1][(t4 * 16 + l15) * 64 + (((s * 4 + quad) ^ rx) * 8)]);
  // (safe: Ps[1] is first overwritten as P in window j=1, after barrier_0)

  floatx4 o_acc[4];
  for (int m = 0; m < 4; ++m) o_acc[m] = zero4;
  float lsum4[4] = {0.f, 0.f, 0.f, 0.f};
  short8 vA0, vA1;  // V_{j-1} B-frags

  for (int j = 0; j <= qt; ++j) {
    const int cj = j & 1, pj = cj ^ 1;

    // ---- issue K_{j+1} A-frags and V_j B-frags (consumed next window)
    short8 kB0, kB1, vB0, vB1;
    if (j < qt) {
      const __hip_bfloat16* kp = kbase + (size_t)((j + 1) * 64 + krow) * QKV;
      kB0 = *reinterpret_cast<const short8*>(kp + quad * 8);
      kB1 = *reinterpret_cast<const short8*>(kp + 32 + quad * 8);
    }
    {
      const __hip_bfloat16* vp = vbase + (size_t)(j * 64 + quad * 8) * QKV + krow;
      for (int i = 0; i < 8; ++i) {
        vB0[i] = *reinterpret_cast<const short*>(vp + (size_t)i * QKV);
        vB1[i] = *reinterpret_cast<const short*>(vp + (size_t)(32 + i) * QKV);
      }
    }

    // ---- PV_{j-1}: all 64 q x wave's 16 d (P parity pj, V regs)
    if (j > 0) {
      for (int s = 0; s < 2; ++s) {
        short8 bv = s ? vA1 : vA0;
        for (int m = 0; m < 4; ++m) {
          short8 ap = *reinterpret_cast<const short8*>(
              &Ps[pj][(m * 16 + l15) * 64 + (((4 * s + quad) ^ rx) * 8)]);
          o_acc[m] = mfma_bf16(ap, bv, o_acc[m]);
        }
      }
    }

    // ---- QK_j: wave's 16 k-rows x all 64 q (K regs)
    floatx4 sc[4];
    for (int t4 = 0; t4 < 4; ++t4) {
      sc[t4] = mfma_bf16(kA0, aq[t4][0], zero4);
      sc[t4] = mfma_bf16(kA1, aq[t4][1], sc[t4]);
    }
    if (j == qt) {  // diagonal mask (local coords)
      int kloc = 16 * wave + quad * 4;
      for (int t4 = 0; t4 < 4; ++t4)
        for (int rg = 0; rg < 4; ++rg)
          if (kloc + rg > t4 * 16 + l15) sc[t4][rg] = -1e30f;
    }

    // ---- exp2 (m=0) + P-write_j (parity cj)
    const int pcol = ((2 * wave + (quad >> 1)) ^ rx) * 8 + (quad & 1) * 4;
    for (int t4 = 0; t4 < 4; ++t4) {
      short pp[4];
      for (int rg = 0; rg < 4; ++rg) {
        float p = exp2_fast(sc[t4][rg]);
        lsum4[t4] += p;
        pp[rg] = bf16s(p);
      }
      *reinterpret_cast<s4v*>(&Ps[cj][(t4 * 16 + l15) * 64 + pcol]) =
          *reinterpret_cast<s4v*>(pp);
    }

    kA0 = kB0; kA1 = kB1; vA0 = vB0; vA1 = vB1;
    __syncthreads();  // single barrier: P_j visible, PV_{j-1} reads done
  }

  // ---- epilogue: PV_qt (V_qt regs, P parity qt&1)
  const int pq = qt & 1;
  for (int s = 0; s < 2; ++s) {
    short8 bv = s ? vA1 : vA0;
    for (int m = 0; m < 4; ++m) {
      short8 ap = *reinterpret_cast<const short8*>(
          &Ps[pq][(m * 16 + l15) * 64 + (((4 * s + quad) ^ rx) * 8)]);
      o_acc[m] = mfma_bf16(ap, bv, o_acc[m]);
    }
  }
  // lsum merge (additive, m=0): quad-reduce then LDS table in the other buffer
  for (int t4 = 0; t4 < 4; ++t4) {
    lsum4[t4] += __shfl_xor(lsum4[t4], 16);
    lsum4[t4] += __shfl_xor(lsum4[t4], 32);
  }
  float* Lf = (float*)&Ps[pq ^ 1][0];  // disjoint from PV_qt reads
  if (quad == 0)
    for (int t4 = 0; t4 < 4; ++t4)
      Lf[wave * 64 + t4 * 16 + l15] = lsum4[t4];
  __syncthreads();
  if (tid < 64)
    Lf[256 + tid] = 1.0f / (Lf[tid] + Lf[64 + tid] + Lf[128 + tid] + Lf[192 + tid]);
  __syncthreads();

  const int dcol = h * 64 + krow;
  for (int m = 0; m < 4; ++m)
    for (int rg = 0; rg < 4; ++rg) {
      int q = m * 16 + quad * 4 + rg;
      out[(size_t)(b * S + q0 + q) * 1024 + dcol] =
          __float2bfloat16(o_acc[m][rg] * Lf[256 + q]);
    }
}

// ---------------------------------------------------------------- launch
extern "C" void kernel_launch(void* const* d_in, const int* in_sizes, int n_in,
                              void* d_out, int out_size, void* d_ws, size_t ws_size,
                              hipStream_t stream) {
  const float* x    = (const float*)d_in[0];
  const float* Wqkv = (const float*)d_in[1];
  const float* bqkv = (const float*)d_in[2];
  const float* Wout = (const float*)d_in[3];
  const float* bout = (const float*)d_in[4];
  float* out = (float*)d_out;

  const int BS = 2 * 2048;
  const int D = 1024;
  char* ws = (char*)d_ws;
  __hip_bfloat16* xb    = (__hip_bfloat16*)(ws);
  __hip_bfloat16* wqkvb = (__hip_bfloat16*)(ws + (size_t)8  * 1048576);
  __hip_bfloat16* wob   = (__hip_bfloat16*)(ws + (size_t)14 * 1048576);
  __hip_bfloat16* qkvb  = (__hip_bfloat16*)(ws + (size_t)16 * 1048576);
  __hip_bfloat16* attnb = (__hip_bfloat16*)(ws + (size_t)40 * 1048576);

  cvt_all<<<4096, 256, 0, stream>>>(x, Wqkv, Wout, xb, wqkvb, wob);

  gemm_256<true><<<dim3(3072 / 256, BS / 256), 512, 0, stream>>>(
      xb, wqkvb, bqkv, qkvb, BS, 3 * D, D);

  flash_attn<<<dim3(32, 16, 2), 256, 0, stream>>>(qkvb, attnb);

  gemm_n64<<<dim3(1024 / 64, BS / 256), 512, 0, stream>>>(
      attnb, wob, bout, out, BS, D, D);
}

// Round 10
// 168.735 us; speedup vs baseline: 1.3430x; 1.3430x over previous
//
#include <hip/hip_runtime.h>
#include <hip/hip_bf16.h>

typedef __attribute__((ext_vector_type(8))) short short8;
typedef __attribute__((ext_vector_type(4))) short s4v;
typedef __attribute__((ext_vector_type(4))) float floatx4;

__device__ inline floatx4 mfma_bf16(short8 a, short8 b, floatx4 c) {
  return __builtin_amdgcn_mfma_f32_16x16x32_bf16(a, b, c, 0, 0, 0);
}
__device__ inline float exp2_fast(float x) { return __builtin_amdgcn_exp2f(x); }

__device__ inline short bf16s(float f) {
  __hip_bfloat16 h = __float2bfloat16(f);
  return *reinterpret_cast<short*>(&h);
}
__device__ inline float sbf16(short s) {
  return __bfloat162float(*reinterpret_cast<__hip_bfloat16*>(&s));
}

// async global->LDS, 16B per lane. LDS dest must be wave-uniform base + lane*16.
__device__ inline void gld16(__hip_bfloat16* lds, const __hip_bfloat16* g) {
  __builtin_amdgcn_global_load_lds(
      (const __attribute__((address_space(1))) void*)g,
      (__attribute__((address_space(3))) void*)lds, 16, 0, 0);
}

// ---------------------------------------------------------------- fused cvt
__global__ __launch_bounds__(256) void cvt_all(
    const float* __restrict__ x, const float* __restrict__ wqkv,
    const float* __restrict__ wout, __hip_bfloat16* __restrict__ xb,
    __hip_bfloat16* __restrict__ wqkvb, __hip_bfloat16* __restrict__ wob) {
  const int n1 = 4194304, n2 = 3145728;  // n3 = 1048576
  int i = (blockIdx.x * 256 + threadIdx.x) * 8;
  const float* src;
  __hip_bfloat16* dst;
  int off;
  if (i < n1) { src = x; dst = xb; off = i; }
  else if (i < n1 + n2) { src = wqkv; dst = wqkvb; off = i - n1; }
  else { src = wout; dst = wob; off = i - n1 - n2; }
  float4 a = *reinterpret_cast<const float4*>(src + off);
  float4 b = *reinterpret_cast<const float4*>(src + off + 4);
  __hip_bfloat16 t[8];
  t[0] = __float2bfloat16(a.x); t[1] = __float2bfloat16(a.y);
  t[2] = __float2bfloat16(a.z); t[3] = __float2bfloat16(a.w);
  t[4] = __float2bfloat16(b.x); t[5] = __float2bfloat16(b.y);
  t[6] = __float2bfloat16(b.z); t[7] = __float2bfloat16(b.w);
  *reinterpret_cast<short8*>(dst + off) = *reinterpret_cast<short8*>(t);
}

// ================================================================ shared GEMM bits
__device__ inline void stage_half(__hip_bfloat16* lds, const __hip_bfloat16* g,
                                  int K, int tid) {
#pragma unroll
  for (int it = 0; it < 2; ++it) {
    int idx = it * 512 + tid;
    int row = idx >> 3, col = ((idx & 7) ^ (row & 7)) * 8;
    gld16(lds + idx * 8, g + (size_t)row * K + col);
  }
}
// 64-row half-size stage (8KB): one gld16 per thread
__device__ inline void stage_q(__hip_bfloat16* lds, const __hip_bfloat16* g,
                               int K, int tid) {
  int row = tid >> 3, col = ((tid & 7) ^ (row & 7)) * 8;
  gld16(lds + tid * 8, g + (size_t)row * K + col);
}

#define VMW(N) asm volatile("s_waitcnt vmcnt(" #N ")" ::: "memory")
#define BAR __builtin_amdgcn_s_barrier()

// ---------------------------------------------------------------- GEMM 256x256 v5 (QKV)
// v4 read-once schedule, SINGLE barrier per phase. Every ds_read is consumed
// by its own phase's MFMA (compiler lgkmcnt's before first use), so a wave's
// reads of buffer cb complete before it reaches the end-of-phase barrier;
// every stage into cb is issued after that barrier -> no DMA-vs-read race.
// Phase = RD; STG; MFMA; WT; BAR.
// Phase order (0,0),(1,0),(1,1),(0,1); stages P1:A0+B0(t+2), P2:A1, P3:B1;
// waits end-P0 vmcnt(10), end-P1 vmcnt(12), end-P3 vmcnt(12) (6-7 ph slack).
// [Register-feasibility note, established r3/r9: with acc = 128 AGPRs, the
// 128-VGPR cap at 2 waves/SIMD admits only this in-phase schedule; read-ahead
// ping-pong variants spill to scratch (r9: WRITE_SIZE 158MB, 94us).]
#define LDA8(dst, BUF, MH)                                                     \
  do {                                                                         \
    _Pragma("unroll") for (int mf = 0; mf < 4; ++mf) {                         \
      int rh = wm * 64 + mf * 16 + l15;                                        \
      _Pragma("unroll") for (int ks = 0; ks < 2; ++ks)                         \
          dst[mf][ks] = *reinterpret_cast<const short8*>(                      \
              &SA[BUF][MH][rh * 64 + (((ks * 4 + quad) ^ (rh & 7)) * 8)]);     \
    }                                                                          \
  } while (0)
#define LDB4(dst, BUF, NH)                                                     \
  do {                                                                         \
    _Pragma("unroll") for (int nf = 0; nf < 2; ++nf) {                         \
      int rh = wn * 32 + nf * 16 + l15;                                        \
      _Pragma("unroll") for (int ks = 0; ks < 2; ++ks)                         \
          dst[nf][ks] = *reinterpret_cast<const short8*>(                      \
              &SB[BUF][NH][rh * 64 + (((ks * 4 + quad) ^ (rh & 7)) * 8)]);     \
    }                                                                          \
  } while (0)
#define MM16(MH, NH, AF, BF)                                                   \
  do {                                                                         \
    _Pragma("unroll") for (int mf = 0; mf < 4; ++mf)                           \
        _Pragma("unroll") for (int nf = 0; nf < 2; ++nf) {                     \
      acc[MH][NH][mf][nf] = mfma_bf16(AF[mf][0], BF[nf][0], acc[MH][NH][mf][nf]); \
      acc[MH][NH][mf][nf] = mfma_bf16(AF[mf][1], BF[nf][1], acc[MH][NH][mf][nf]); \
    }                                                                          \
  } while (0)
#define PH(RD, STG, MH, NH, AF, BF, WT)                                        \
  do {                                                                         \
    RD;                                                                        \
    STG;                                                                       \
    __builtin_amdgcn_s_setprio(1);                                             \
    MM16(MH, NH, AF, BF);                                                      \
    __builtin_amdgcn_s_setprio(0);                                             \
    WT;                                                                        \
    BAR;                                                                       \
  } while (0)

template<bool OUT_BF16>
__global__ __launch_bounds__(512, 2) void gemm_256(
    const __hip_bfloat16* __restrict__ A, const __hip_bfloat16* __restrict__ Bt,
    const float* __restrict__ bias, void* __restrict__ Cout,
    int M, int N, int K) {
  __shared__ __align__(16) __hip_bfloat16 SA[2][2][128 * 64];
  __shared__ __align__(16) __hip_bfloat16 SB[2][2][128 * 64];
  const int tid = threadIdx.x;
  const int lane = tid & 63, quad = (lane >> 4), l15 = lane & 15;
  const int wave = tid >> 6;
  const int wm = wave >> 2, wn = wave & 3;

  // bijective XCD swizzle (nwg % 8 == 0 for our shapes)
  const int nbx = gridDim.x;
  int bid = blockIdx.y * nbx + blockIdx.x;
  const int nwg = nbx * gridDim.y;
  if ((nwg & 7) == 0) bid = (bid & 7) * (nwg >> 3) + (bid >> 3);
  const int bx = bid % nbx, by = bid / nbx;
  const int m0 = by * 256, n0 = bx * 256;

  const __hip_bfloat16* Abase = A + (size_t)m0 * K;
  const __hip_bfloat16* Bbase = Bt + (size_t)n0 * K;
  const int NT = K >> 6;  // requires NT >= 3

  floatx4 acc[2][2][4][2];
#pragma unroll
  for (int a = 0; a < 2; ++a)
#pragma unroll
    for (int b = 0; b < 2; ++b)
#pragma unroll
      for (int c = 0; c < 4; ++c)
#pragma unroll
        for (int d = 0; d < 2; ++d) acc[a][b][c][d] = (floatx4){0.f, 0.f, 0.f, 0.f};

  short8 af0[4][2], af1[4][2];  // A frags mh0 (live P0-P3), mh1 (live P1-P2)
  short8 bf0[2][2], bf1[2][2];  // B frags nh0 (live P0-P1), nh1 (live P2-P3)

  // ---- prologue: tiles 0,1 in steady issue order {A0,B0,A1,B1}
  stage_half(&SA[0][0][0], Abase, K, tid);
  stage_half(&SB[0][0][0], Bbase, K, tid);
  stage_half(&SA[0][1][0], Abase + (size_t)128 * K, K, tid);
  stage_half(&SB[0][1][0], Bbase + (size_t)128 * K, K, tid);
  stage_half(&SA[1][0][0], Abase + 64, K, tid);
  stage_half(&SB[1][0][0], Bbase + 64, K, tid);
  stage_half(&SA[1][1][0], Abase + (size_t)128 * K + 64, K, tid);
  stage_half(&SB[1][1][0], Bbase + (size_t)128 * K + 64, K, tid);
  VMW(12);  // forces A0(0),B0(0)
  BAR;

  // ---- steady: t in [0, NT-3], stage tile t+2 into buffer cb
  for (int t = 0; t <= NT - 3; ++t) {
    const int cb = t & 1;
    const size_t k2 = (size_t)(t + 2) * 64;
    PH({ LDA8(af0, cb, 0); LDB4(bf0, cb, 0); }, (void)0,
       0, 0, af0, bf0, VMW(10));
    PH(LDA8(af1, cb, 1),
       { stage_half(&SA[cb][0][0], Abase + k2, K, tid);
         stage_half(&SB[cb][0][0], Bbase + k2, K, tid); },
       1, 0, af1, bf0, VMW(12));
    PH(LDB4(bf1, cb, 1),
       stage_half(&SA[cb][1][0], Abase + (size_t)128 * K + k2, K, tid),
       1, 1, af1, bf1, (void)0);
    PH((void)0,
       stage_half(&SB[cb][1][0], Bbase + (size_t)128 * K + k2, K, tid),
       0, 1, af0, bf1, VMW(12));
  }
  {  // ---- t = NT-2: no stages, draining waits
    const int cb = (NT - 2) & 1;
    PH({ LDA8(af0, cb, 0); LDB4(bf0, cb, 0); }, (void)0, 0, 0, af0, bf0, VMW(10));
    PH(LDA8(af1, cb, 1), (void)0, 1, 0, af1, bf0, VMW(8));
    PH(LDB4(bf1, cb, 1), (void)0, 1, 1, af1, bf1, (void)0);
    PH((void)0, (void)0, 0, 1, af0, bf1, VMW(4));
  }
  {  // ---- t = NT-1: final tile
    const int cb = (NT - 1) & 1;
    PH({ LDA8(af0, cb, 0); LDB4(bf0, cb, 0); }, (void)0, 0, 0, af0, bf0, VMW(2));
    PH(LDA8(af1, cb, 1), (void)0, 1, 0, af1, bf0, VMW(0));
    LDB4(bf1, cb, 1);
    __builtin_amdgcn_s_setprio(1);
    MM16(1, 1, af1, bf1);
    MM16(0, 1, af0, bf1);
    __builtin_amdgcn_s_setprio(0);
  }

  // ---- epilogue
#pragma unroll
  for (int nh = 0; nh < 2; ++nh)
#pragma unroll
    for (int nf = 0; nf < 2; ++nf) {
      int gn = n0 + nh * 128 + wn * 32 + nf * 16 + l15;
      float bv = bias[gn];
#pragma unroll
      for (int mh = 0; mh < 2; ++mh)
#pragma unroll
        for (int mf = 0; mf < 4; ++mf)
#pragma unroll
          for (int rg = 0; rg < 4; ++rg) {
            int gm = m0 + mh * 128 + wm * 64 + mf * 16 + quad * 4 + rg;
            float v = acc[mh][nh][mf][nf][rg] + bv;
            if (OUT_BF16)
              ((__hip_bfloat16*)Cout)[(size_t)gm * N + gn] = __float2bfloat16(v);
            else
              ((float*)Cout)[(size_t)gm * N + gn] = v;
          }
    }
}

// ---------------------------------------------------------------- GEMM 256x64 (out-proj) v3
// Triple-buffered, ONE phase per K-tile, ONE barrier per phase.
// Phase t: read A0,A1,B from buf cb=t%3; stage tile t+2 -> buf (t+2)%3
// (that slot's last read was phase t-1, whose reads completed before its
// end-barrier; stages are issued after that barrier -> race-safe);
// 16 MFMA; VMW(5) forces phase t-1's stage (tile t+1, 1-phase slack); BAR.
// Prologue: t0+t1 (10 loads), VMW(5) forces t0. Tail: t=NT-2 VMW(0); t=NT-1
// no wait/barrier. LDS: 3x32KB A + 3x8KB B = 120KB -> 1 block/CU.
__global__ __launch_bounds__(512, 2) void gemm_n64(
    const __hip_bfloat16* __restrict__ A, const __hip_bfloat16* __restrict__ Bt,
    const float* __restrict__ bias, float* __restrict__ Cout,
    int M, int N, int K) {
  __shared__ __align__(16) __hip_bfloat16 SA[3][2][128 * 64];
  __shared__ __align__(16) __hip_bfloat16 SB[3][64 * 64];
  const int tid = threadIdx.x;
  const int lane = tid & 63, quad = (lane >> 4), l15 = lane & 15;
  const int wave = tid >> 6;
  const int wm = wave >> 2, wn = wave & 3;

  const int nbx = gridDim.x;
  int bid = blockIdx.y * nbx + blockIdx.x;
  const int nwg = nbx * gridDim.y;
  if ((nwg & 7) == 0) bid = (bid & 7) * (nwg >> 3) + (bid >> 3);
  const int bx = bid % nbx, by = bid / nbx;
  const int m0 = by * 256, n0 = bx * 64;

  const __hip_bfloat16* Abase = A + (size_t)m0 * K;
  const __hip_bfloat16* Bbase = Bt + (size_t)n0 * K;
  const int NT = K >> 6;  // requires NT >= 3

  floatx4 acc[2][4];
#pragma unroll
  for (int a = 0; a < 2; ++a)
#pragma unroll
    for (int c = 0; c < 4; ++c) acc[a][c] = (floatx4){0.f, 0.f, 0.f, 0.f};

  short8 af0[4][2], af1[4][2];  // A frags mh0 / mh1
  short8 bf[2];                 // B frags (wave's 16 cols)

#define N64_LDA(dst, BUF, MH)                                                  \
  do {                                                                         \
    _Pragma("unroll") for (int mf = 0; mf < 4; ++mf) {                         \
      int rh = wm * 64 + mf * 16 + l15;                                        \
      _Pragma("unroll") for (int ks = 0; ks < 2; ++ks)                         \
          dst[mf][ks] = *reinterpret_cast<const short8*>(                      \
              &SA[BUF][MH][rh * 64 + (((ks * 4 + quad) ^ (rh & 7)) * 8)]);     \
    }                                                                          \
  } while (0)
#define N64_LDB(BUF)                                                           \
  do {                                                                         \
    int rh = wn * 16 + l15;                                                    \
    _Pragma("unroll") for (int ks = 0; ks < 2; ++ks)                           \
        bf[ks] = *reinterpret_cast<const short8*>(                             \
            &SB[BUF][rh * 64 + (((ks * 4 + quad) ^ (rh & 7)) * 8)]);           \
  } while (0)
#define N64_MM(MH, AF)                                                         \
  do {                                                                         \
    _Pragma("unroll") for (int mf = 0; mf < 4; ++mf) {                         \
      acc[MH][mf] = mfma_bf16(AF[mf][0], bf[0], acc[MH][mf]);                  \
      acc[MH][mf] = mfma_bf16(AF[mf][1], bf[1], acc[MH][mf]);                  \
    }                                                                          \
  } while (0)

  // ---- prologue: t0 -> buf0, t1 -> buf1 (order per tile: A0,A1,B)
  stage_half(&SA[0][0][0], Abase, K, tid);
  stage_half(&SA[0][1][0], Abase + (size_t)128 * K, K, tid);
  stage_q(&SB[0][0], Bbase, K, tid);
  stage_half(&SA[1][0][0], Abase + 64, K, tid);
  stage_half(&SA[1][1][0], Abase + (size_t)128 * K + 64, K, tid);
  stage_q(&SB[1][0], Bbase + 64, K, tid);
  VMW(5);  // forces tile 0
  BAR;

  int cb = 0, sb = 2;
  for (int t = 0; t <= NT - 3; ++t) {
    const size_t k2 = (size_t)(t + 2) * 64;
    N64_LDA(af0, cb, 0);
    N64_LDA(af1, cb, 1);
    N64_LDB(cb);
    stage_half(&SA[sb][0][0], Abase + k2, K, tid);
    stage_half(&SA[sb][1][0], Abase + (size_t)128 * K + k2, K, tid);
    stage_q(&SB[sb][0], Bbase + k2, K, tid);
    __builtin_amdgcn_s_setprio(1);
    N64_MM(0, af0);
    N64_MM(1, af1);
    __builtin_amdgcn_s_setprio(0);
    VMW(5);  // forces tile t+1 (staged at phase t-1)
    BAR;
    cb = (cb == 2) ? 0 : cb + 1;
    sb = (sb == 2) ? 0 : sb + 1;
  }
  {  // ---- t = NT-2: no stage, drain tile NT-1
    N64_LDA(af0, cb, 0);
    N64_LDA(af1, cb, 1);
    N64_LDB(cb);
    __builtin_amdgcn_s_setprio(1);
    N64_MM(0, af0);
    N64_MM(1, af1);
    __builtin_amdgcn_s_setprio(0);
    VMW(0);
    BAR;
    cb = (cb == 2) ? 0 : cb + 1;
  }
  {  // ---- t = NT-1
    N64_LDA(af0, cb, 0);
    N64_LDA(af1, cb, 1);
    N64_LDB(cb);
    __builtin_amdgcn_s_setprio(1);
    N64_MM(0, af0);
    N64_MM(1, af1);
    __builtin_amdgcn_s_setprio(0);
  }

  // ---- epilogue (fp32 out)
  {
    int gn = n0 + wn * 16 + l15;
    float bv = bias[gn];
#pragma unroll
    for (int mh = 0; mh < 2; ++mh)
#pragma unroll
      for (int mf = 0; mf < 4; ++mf)
#pragma unroll
        for (int rg = 0; rg < 4; ++rg) {
          int gm = m0 + mh * 128 + wm * 64 + mf * 16 + quad * 4 + rg;
          Cout[(size_t)gm * N + gn] = acc[mh][mf][rg] + bv;
        }
  }
#undef N64_LDA
#undef N64_LDB
#undef N64_MM
}

// ---------------------------------------------------------------- flash attn v11
// v10 structure; launch_bounds (256,3) — part of the best measured config
// (167.6us, r7). VGPR headroom ~170 while keeping 3 blocks/CU.
__global__ __launch_bounds__(256, 3) void flash_attn(
    const __hip_bfloat16* __restrict__ qkv, __hip_bfloat16* __restrict__ out) {
  const int S = 2048, QKV = 3072;
  const int bx = blockIdx.x;
  const int g = (blockIdx.y >> 3) + 2 * blockIdx.z;
  int qt;
  if (g == 0)      qt = bx;
  else if (g == 1) qt = 31 - bx;
  else if (g == 2) qt = (bx + 8) & 31;
  else             qt = (23 - bx) & 31;
  const int h = blockIdx.y, b = blockIdx.z;
  const int q0 = qt * 64;
  __shared__ __align__(16) short Ps[2][64 * 64];  // P double-buffer; Ps[1] stages Q
  const int tid = threadIdx.x;
  const int wave = tid >> 6, lane = tid & 63, quad = lane >> 4, l15 = lane & 15;
  const int rx = l15 & 7;
  const __hip_bfloat16* base = qkv + (size_t)b * S * QKV;
  const float c2 = 0.18033688011112042f;  // (1/sqrt(64)) * log2(e)
  const floatx4 zero4 = {0.f, 0.f, 0.f, 0.f};
  const int krow = 16 * wave + l15;  // wave's K-row (QK) and d-column (PV)

  const __hip_bfloat16* kbase = base + 1024 + h * 64;  // K plane
  const __hip_bfloat16* vbase = base + 2048 + h * 64;  // V plane

  // ---- prologue: Q (scaled) -> Ps[1]; K_0 frags -> regs
  for (int it = 0; it < 2; ++it) {
    int v = tid + it * 256;
    int row = v >> 3, cb = v & 7;
    int colp = (cb ^ (row & 7)) * 8;
    short8 qv = *reinterpret_cast<const short8*>(
        base + (size_t)(q0 + row) * QKV + h * 64 + cb * 8);
    short qs[8];
    for (int e = 0; e < 8; ++e) qs[e] = bf16s(sbf16(qv[e]) * c2);
    *reinterpret_cast<short8*>(&Ps[1][row * 64 + colp]) = *reinterpret_cast<short8*>(qs);
  }
  short8 kA0 = *reinterpret_cast<const short8*>(
      kbase + (size_t)krow * QKV + quad * 8);
  short8 kA1 = *reinterpret_cast<const short8*>(
      kbase + (size_t)krow * QKV + 32 + quad * 8);
  __syncthreads();  // Q visible

  short8 aq[4][2];  // Q B-frags: all 64 q rows x both d-halves
  for (int t4 = 0; t4 < 4; ++t4)
    for (int s = 0; s < 2; ++s)
      aq[t4][s] = *reinterpret_cast<const short8*>(
          &Ps[1][(t4 * 16 + l15) * 64 + (((s * 4 + quad) ^ rx) * 8)]);
  // (safe: Ps[1] is first overwritten as P in window j=1, after barrier_0)

  floatx4 o_acc[4];
  for (int m = 0; m < 4; ++m) o_acc[m] = zero4;
  float lsum4[4] = {0.f, 0.f, 0.f, 0.f};
  short8 vA0, vA1;  // V_{j-1} B-frags

  for (int j = 0; j <= qt; ++j) {
    const int cj = j & 1, pj = cj ^ 1;

    // ---- issue K_{j+1} A-frags and V_j B-frags (consumed next window)
    short8 kB0, kB1, vB0, vB1;
    if (j < qt) {
      const __hip_bfloat16* kp = kbase + (size_t)((j + 1) * 64 + krow) * QKV;
      kB0 = *reinterpret_cast<const short8*>(kp + quad * 8);
      kB1 = *reinterpret_cast<const short8*>(kp + 32 + quad * 8);
    }
    {
      const __hip_bfloat16* vp = vbase + (size_t)(j * 64 + quad * 8) * QKV + krow;
      for (int i = 0; i < 8; ++i) {
        vB0[i] = *reinterpret_cast<const short*>(vp + (size_t)i * QKV);
        vB1[i] = *reinterpret_cast<const short*>(vp + (size_t)(32 + i) * QKV);
      }
    }

    // ---- PV_{j-1}: all 64 q x wave's 16 d (P parity pj, V regs)
    if (j > 0) {
      for (int s = 0; s < 2; ++s) {
        short8 bv = s ? vA1 : vA0;
        for (int m = 0; m < 4; ++m) {
          short8 ap = *reinterpret_cast<const short8*>(
              &Ps[pj][(m * 16 + l15) * 64 + (((4 * s + quad) ^ rx) * 8)]);
          o_acc[m] = mfma_bf16(ap, bv, o_acc[m]);
        }
      }
    }

    // ---- QK_j: wave's 16 k-rows x all 64 q (K regs)
    floatx4 sc[4];
    for (int t4 = 0; t4 < 4; ++t4) {
      sc[t4] = mfma_bf16(kA0, aq[t4][0], zero4);
      sc[t4] = mfma_bf16(kA1, aq[t4][1], sc[t4]);
    }
    if (j == qt) {  // diagonal mask (local coords)
      int kloc = 16 * wave + quad * 4;
      for (int t4 = 0; t4 < 4; ++t4)
        for (int rg = 0; rg < 4; ++rg)
          if (kloc + rg > t4 * 16 + l15) sc[t4][rg] = -1e30f;
    }

    // ---- exp2 (m=0) + P-write_j (parity cj)
    const int pcol = ((2 * wave + (quad >> 1)) ^ rx) * 8 + (quad & 1) * 4;
    for (int t4 = 0; t4 < 4; ++t4) {
      short pp[4];
      for (int rg = 0; rg < 4; ++rg) {
        float p = exp2_fast(sc[t4][rg]);
        lsum4[t4] += p;
        pp[rg] = bf16s(p);
      }
      *reinterpret_cast<s4v*>(&Ps[cj][(t4 * 16 + l15) * 64 + pcol]) =
          *reinterpret_cast<s4v*>(pp);
    }

    kA0 = kB0; kA1 = kB1; vA0 = vB0; vA1 = vB1;
    __syncthreads();  // single barrier: P_j visible, PV_{j-1} reads done
  }

  // ---- epilogue: PV_qt (V_qt regs, P parity qt&1)
  const int pq = qt & 1;
  for (int s = 0; s < 2; ++s) {
    short8 bv = s ? vA1 : vA0;
    for (int m = 0; m < 4; ++m) {
      short8 ap = *reinterpret_cast<const short8*>(
          &Ps[pq][(m * 16 + l15) * 64 + (((4 * s + quad) ^ rx) * 8)]);
      o_acc[m] = mfma_bf16(ap, bv, o_acc[m]);
    }
  }
  // lsum merge (additive, m=0): quad-reduce then LDS table in the other buffer
  for (int t4 = 0; t4 < 4; ++t4) {
    lsum4[t4] += __shfl_xor(lsum4[t4], 16);
    lsum4[t4] += __shfl_xor(lsum4[t4], 32);
  }
  float* Lf = (float*)&Ps[pq ^ 1][0];  // disjoint from PV_qt reads
  if (quad == 0)
    for (int t4 = 0; t4 < 4; ++t4)
      Lf[wave * 64 + t4 * 16 + l15] = lsum4[t4];
  __syncthreads();
  if (tid < 64)
    Lf[256 + tid] = 1.0f / (Lf[tid] + Lf[64 + tid] + Lf[128 + tid] + Lf[192 + tid]);
  __syncthreads();

  const int dcol = h * 64 + krow;
  for (int m = 0; m < 4; ++m)
    for (int rg = 0; rg < 4; ++rg) {
      int q = m * 16 + quad * 4 + rg;
      out[(size_t)(b * S + q0 + q) * 1024 + dcol] =
          __float2bfloat16(o_acc[m][rg] * Lf[256 + q]);
    }
}

// ---------------------------------------------------------------- launch
extern "C" void kernel_launch(void* const* d_in, const int* in_sizes, int n_in,
                              void* d_out, int out_size, void* d_ws, size_t ws_size,
                              hipStream_t stream) {
  const float* x    = (const float*)d_in[0];
  const float* Wqkv = (const float*)d_in[1];
  const float* bqkv = (const float*)d_in[2];
  const float* Wout = (const float*)d_in[3];
  const float* bout = (const float*)d_in[4];
  float* out = (float*)d_out;

  const int BS = 2 * 2048;
  const int D = 1024;
  char* ws = (char*)d_ws;
  __hip_bfloat16* xb    = (__hip_bfloat16*)(ws);
  __hip_bfloat16* wqkvb = (__hip_bfloat16*)(ws + (size_t)8  * 1048576);
  __hip_bfloat16* wob   = (__hip_bfloat16*)(ws + (size_t)14 * 1048576);
  __hip_bfloat16* qkvb  = (__hip_bfloat16*)(ws + (size_t)16 * 1048576);
  __hip_bfloat16* attnb = (__hip_bfloat16*)(ws + (size_t)40 * 1048576);

  cvt_all<<<4096, 256, 0, stream>>>(x, Wqkv, Wout, xb, wqkvb, wob);

  gemm_256<true><<<dim3(3072 / 256, BS / 256), 512, 0, stream>>>(
      xb, wqkvb, bqkv, qkvb, BS, 3 * D, D);

  flash_attn<<<dim3(32, 16, 2), 256, 0, stream>>>(qkvb, attnb);

  gemm_n64<<<dim3(1024 / 64, BS / 256), 512, 0, stream>>>(
      attnb, wob, bout, out, BS, D, D);
}

// Round 11
// 165.324 us; speedup vs baseline: 1.3707x; 1.0206x over previous
//
#include <hip/hip_runtime.h>
#include <hip/hip_bf16.h>

typedef __attribute__((ext_vector_type(8))) short short8;
typedef __attribute__((ext_vector_type(4))) short s4v;
typedef __attribute__((ext_vector_type(4))) float floatx4;

__device__ inline floatx4 mfma_bf16(short8 a, short8 b, floatx4 c) {
  return __builtin_amdgcn_mfma_f32_16x16x32_bf16(a, b, c, 0, 0, 0);
}
__device__ inline float exp2_fast(float x) { return __builtin_amdgcn_exp2f(x); }

__device__ inline short bf16s(float f) {
  __hip_bfloat16 h = __float2bfloat16(f);
  return *reinterpret_cast<short*>(&h);
}
__device__ inline float sbf16(short s) {
  return __bfloat162float(*reinterpret_cast<__hip_bfloat16*>(&s));
}

// async global->LDS, 16B per lane. LDS dest must be wave-uniform base + lane*16.
__device__ inline void gld16(__hip_bfloat16* lds, const __hip_bfloat16* g) {
  __builtin_amdgcn_global_load_lds(
      (const __attribute__((address_space(1))) void*)g,
      (__attribute__((address_space(3))) void*)lds, 16, 0, 0);
}

// ---------------------------------------------------------------- fused cvt
__global__ __launch_bounds__(256) void cvt_all(
    const float* __restrict__ x, const float* __restrict__ wqkv,
    const float* __restrict__ wout, __hip_bfloat16* __restrict__ xb,
    __hip_bfloat16* __restrict__ wqkvb, __hip_bfloat16* __restrict__ wob) {
  const int n1 = 4194304, n2 = 3145728;  // n3 = 1048576
  int i = (blockIdx.x * 256 + threadIdx.x) * 8;
  const float* src;
  __hip_bfloat16* dst;
  int off;
  if (i < n1) { src = x; dst = xb; off = i; }
  else if (i < n1 + n2) { src = wqkv; dst = wqkvb; off = i - n1; }
  else { src = wout; dst = wob; off = i - n1 - n2; }
  float4 a = *reinterpret_cast<const float4*>(src + off);
  float4 b = *reinterpret_cast<const float4*>(src + off + 4);
  __hip_bfloat16 t[8];
  t[0] = __float2bfloat16(a.x); t[1] = __float2bfloat16(a.y);
  t[2] = __float2bfloat16(a.z); t[3] = __float2bfloat16(a.w);
  t[4] = __float2bfloat16(b.x); t[5] = __float2bfloat16(b.y);
  t[6] = __float2bfloat16(b.z); t[7] = __float2bfloat16(b.w);
  *reinterpret_cast<short8*>(dst + off) = *reinterpret_cast<short8*>(t);
}

// ================================================================ shared GEMM bits
__device__ inline void stage_half(__hip_bfloat16* lds, const __hip_bfloat16* g,
                                  int K, int tid) {
#pragma unroll
  for (int it = 0; it < 2; ++it) {
    int idx = it * 512 + tid;
    int row = idx >> 3, col = ((idx & 7) ^ (row & 7)) * 8;
    gld16(lds + idx * 8, g + (size_t)row * K + col);
  }
}
// 256-thread variants: A tile 128x64 (16KB, 4 iters), B tile 64x64 (8KB, 2 iters)
__device__ inline void stage_a128_t256(__hip_bfloat16* lds, const __hip_bfloat16* g,
                                       int K, int tid) {
#pragma unroll
  for (int it = 0; it < 4; ++it) {
    int idx = it * 256 + tid;
    int row = idx >> 3, col = ((idx & 7) ^ (row & 7)) * 8;
    gld16(lds + idx * 8, g + (size_t)row * K + col);
  }
}
__device__ inline void stage_b64_t256(__hip_bfloat16* lds, const __hip_bfloat16* g,
                                      int K, int tid) {
#pragma unroll
  for (int it = 0; it < 2; ++it) {
    int idx = it * 256 + tid;
    int row = idx >> 3, col = ((idx & 7) ^ (row & 7)) * 8;
    gld16(lds + idx * 8, g + (size_t)row * K + col);
  }
}

#define VMW(N) asm volatile("s_waitcnt vmcnt(" #N ")" ::: "memory")
#define BAR __builtin_amdgcn_s_barrier()

// ---------------------------------------------------------------- GEMM 256x256 v5 (QKV)
// v4 read-once schedule, SINGLE barrier per phase. Every ds_read is consumed
// by its own phase's MFMA (compiler lgkmcnt's before first use), so a wave's
// reads of buffer cb complete before it reaches the end-of-phase barrier;
// every stage into cb is issued after that barrier -> no DMA-vs-read race.
// Phase = RD; STG; MFMA; WT; BAR.
// Phase order (0,0),(1,0),(1,1),(0,1); stages P1:A0+B0(t+2), P2:A1, P3:B1;
// waits end-P0 vmcnt(10), end-P1 vmcnt(12), end-P3 vmcnt(12) (6-7 ph slack).
// [Register-feasibility, established r3/r9: gfx950 unified VGPR/AGPR file:
// acc(128 AGPR) + 2 waves/SIMD -> 128 arch-VGPR cap; only this in-phase
// schedule fits. Read-ahead ping-pong spills (r9: WRITE_SIZE 158MB, 94us).]
#define LDA8(dst, BUF, MH)                                                     \
  do {                                                                         \
    _Pragma("unroll") for (int mf = 0; mf < 4; ++mf) {                         \
      int rh = wm * 64 + mf * 16 + l15;                                        \
      _Pragma("unroll") for (int ks = 0; ks < 2; ++ks)                         \
          dst[mf][ks] = *reinterpret_cast<const short8*>(                      \
              &SA[BUF][MH][rh * 64 + (((ks * 4 + quad) ^ (rh & 7)) * 8)]);     \
    }                                                                          \
  } while (0)
#define LDB4(dst, BUF, NH)                                                     \
  do {                                                                         \
    _Pragma("unroll") for (int nf = 0; nf < 2; ++nf) {                         \
      int rh = wn * 32 + nf * 16 + l15;                                        \
      _Pragma("unroll") for (int ks = 0; ks < 2; ++ks)                         \
          dst[nf][ks] = *reinterpret_cast<const short8*>(                      \
              &SB[BUF][NH][rh * 64 + (((ks * 4 + quad) ^ (rh & 7)) * 8)]);     \
    }                                                                          \
  } while (0)
#define MM16(MH, NH, AF, BF)                                                   \
  do {                                                                         \
    _Pragma("unroll") for (int mf = 0; mf < 4; ++mf)                           \
        _Pragma("unroll") for (int nf = 0; nf < 2; ++nf) {                     \
      acc[MH][NH][mf][nf] = mfma_bf16(AF[mf][0], BF[nf][0], acc[MH][NH][mf][nf]); \
      acc[MH][NH][mf][nf] = mfma_bf16(AF[mf][1], BF[nf][1], acc[MH][NH][mf][nf]); \
    }                                                                          \
  } while (0)
#define PH(RD, STG, MH, NH, AF, BF, WT)                                        \
  do {                                                                         \
    RD;                                                                        \
    STG;                                                                       \
    __builtin_amdgcn_s_setprio(1);                                             \
    MM16(MH, NH, AF, BF);                                                      \
    __builtin_amdgcn_s_setprio(0);                                             \
    WT;                                                                        \
    BAR;                                                                       \
  } while (0)

template<bool OUT_BF16>
__global__ __launch_bounds__(512, 2) void gemm_256(
    const __hip_bfloat16* __restrict__ A, const __hip_bfloat16* __restrict__ Bt,
    const float* __restrict__ bias, void* __restrict__ Cout,
    int M, int N, int K) {
  __shared__ __align__(16) __hip_bfloat16 SA[2][2][128 * 64];
  __shared__ __align__(16) __hip_bfloat16 SB[2][2][128 * 64];
  const int tid = threadIdx.x;
  const int lane = tid & 63, quad = (lane >> 4), l15 = lane & 15;
  const int wave = tid >> 6;
  const int wm = wave >> 2, wn = wave & 3;

  // bijective XCD swizzle (nwg % 8 == 0 for our shapes)
  const int nbx = gridDim.x;
  int bid = blockIdx.y * nbx + blockIdx.x;
  const int nwg = nbx * gridDim.y;
  if ((nwg & 7) == 0) bid = (bid & 7) * (nwg >> 3) + (bid >> 3);
  const int bx = bid % nbx, by = bid / nbx;
  const int m0 = by * 256, n0 = bx * 256;

  const __hip_bfloat16* Abase = A + (size_t)m0 * K;
  const __hip_bfloat16* Bbase = Bt + (size_t)n0 * K;
  const int NT = K >> 6;  // requires NT >= 3

  floatx4 acc[2][2][4][2];
#pragma unroll
  for (int a = 0; a < 2; ++a)
#pragma unroll
    for (int b = 0; b < 2; ++b)
#pragma unroll
      for (int c = 0; c < 4; ++c)
#pragma unroll
        for (int d = 0; d < 2; ++d) acc[a][b][c][d] = (floatx4){0.f, 0.f, 0.f, 0.f};

  short8 af0[4][2], af1[4][2];  // A frags mh0 (live P0-P3), mh1 (live P1-P2)
  short8 bf0[2][2], bf1[2][2];  // B frags nh0 (live P0-P1), nh1 (live P2-P3)

  // ---- prologue: tiles 0,1 in steady issue order {A0,B0,A1,B1}
  stage_half(&SA[0][0][0], Abase, K, tid);
  stage_half(&SB[0][0][0], Bbase, K, tid);
  stage_half(&SA[0][1][0], Abase + (size_t)128 * K, K, tid);
  stage_half(&SB[0][1][0], Bbase + (size_t)128 * K, K, tid);
  stage_half(&SA[1][0][0], Abase + 64, K, tid);
  stage_half(&SB[1][0][0], Bbase + 64, K, tid);
  stage_half(&SA[1][1][0], Abase + (size_t)128 * K + 64, K, tid);
  stage_half(&SB[1][1][0], Bbase + (size_t)128 * K + 64, K, tid);
  VMW(12);  // forces A0(0),B0(0)
  BAR;

  // ---- steady: t in [0, NT-3], stage tile t+2 into buffer cb
  for (int t = 0; t <= NT - 3; ++t) {
    const int cb = t & 1;
    const size_t k2 = (size_t)(t + 2) * 64;
    PH({ LDA8(af0, cb, 0); LDB4(bf0, cb, 0); }, (void)0,
       0, 0, af0, bf0, VMW(10));
    PH(LDA8(af1, cb, 1),
       { stage_half(&SA[cb][0][0], Abase + k2, K, tid);
         stage_half(&SB[cb][0][0], Bbase + k2, K, tid); },
       1, 0, af1, bf0, VMW(12));
    PH(LDB4(bf1, cb, 1),
       stage_half(&SA[cb][1][0], Abase + (size_t)128 * K + k2, K, tid),
       1, 1, af1, bf1, (void)0);
    PH((void)0,
       stage_half(&SB[cb][1][0], Bbase + (size_t)128 * K + k2, K, tid),
       0, 1, af0, bf1, VMW(12));
  }
  {  // ---- t = NT-2: no stages, draining waits
    const int cb = (NT - 2) & 1;
    PH({ LDA8(af0, cb, 0); LDB4(bf0, cb, 0); }, (void)0, 0, 0, af0, bf0, VMW(10));
    PH(LDA8(af1, cb, 1), (void)0, 1, 0, af1, bf0, VMW(8));
    PH(LDB4(bf1, cb, 1), (void)0, 1, 1, af1, bf1, (void)0);
    PH((void)0, (void)0, 0, 1, af0, bf1, VMW(4));
  }
  {  // ---- t = NT-1: final tile
    const int cb = (NT - 1) & 1;
    PH({ LDA8(af0, cb, 0); LDB4(bf0, cb, 0); }, (void)0, 0, 0, af0, bf0, VMW(2));
    PH(LDA8(af1, cb, 1), (void)0, 1, 0, af1, bf0, VMW(0));
    LDB4(bf1, cb, 1);
    __builtin_amdgcn_s_setprio(1);
    MM16(1, 1, af1, bf1);
    MM16(0, 1, af0, bf1);
    __builtin_amdgcn_s_setprio(0);
  }

  // ---- epilogue
#pragma unroll
  for (int nh = 0; nh < 2; ++nh)
#pragma unroll
    for (int nf = 0; nf < 2; ++nf) {
      int gn = n0 + nh * 128 + wn * 32 + nf * 16 + l15;
      float bv = bias[gn];
#pragma unroll
      for (int mh = 0; mh < 2; ++mh)
#pragma unroll
        for (int mf = 0; mf < 4; ++mf)
#pragma unroll
          for (int rg = 0; rg < 4; ++rg) {
            int gm = m0 + mh * 128 + wm * 64 + mf * 16 + quad * 4 + rg;
            float v = acc[mh][nh][mf][nf][rg] + bv;
            if (OUT_BF16)
              ((__hip_bfloat16*)Cout)[(size_t)gm * N + gn] = __float2bfloat16(v);
            else
              ((float*)Cout)[(size_t)gm * N + gn] = v;
          }
    }
}

// ---------------------------------------------------------------- GEMM 128x64 (out-proj) v4
// TLP variant: gemm_bt<64> geometry (indices r0-verified) + v3 triple-buffer
// pipeline. 256 thr = 4 waves (2M x 2N), per-wave 64x32 out (acc 32 AGPR).
// LDS: 3 x (A 16KB + B 8KB) = 72KB -> 2 blocks/CU; grid (16,32)=512 = 2/CU.
// When one block stalls on its VMW, the co-resident block's waves run (m114
// implicit TLP) — the lever the 1-block/CU v3 lacked.
// Phase t: read A,B from buf cb=t%3 (12 ds_read, consumed in-phase);
//   stage tile t+2 -> buf (t+2)%3 (slot's last read = phase t-1, sealed by
//   its end barrier -> no DMA race); 16 MFMA; VMW(6) forces tile t+1
//   (12 outstanding: 6 of t+1 issued @t-1 + 6 of t+2 issued @t); BAR.
// Prologue: stage t0,t1 (12 loads), VMW(6) forces t0. Tails: NT-2 -> VMW(0);
// NT-1 -> none. Requires NT >= 3.
__global__ __launch_bounds__(256, 2) void gemm_n64b(
    const __hip_bfloat16* __restrict__ A, const __hip_bfloat16* __restrict__ Bt,
    const float* __restrict__ bias, float* __restrict__ Cout,
    int M, int N, int K) {
  __shared__ __align__(16) __hip_bfloat16 SA[3][128 * 64];
  __shared__ __align__(16) __hip_bfloat16 SB[3][64 * 64];
  const int tid = threadIdx.x;
  const int wave = tid >> 6, lane = tid & 63, quad = lane >> 4, l15 = lane & 15;
  const int wm = (wave >> 1) * 64, wn = (wave & 1) * 32;

  const int nbx = gridDim.x;
  int bid = blockIdx.y * nbx + blockIdx.x;
  const int nwg = nbx * gridDim.y;
  if ((nwg & 7) == 0) bid = (bid & 7) * (nwg >> 3) + (bid >> 3);
  const int bx = bid % nbx, by = bid / nbx;
  const int m0 = by * 128, n0 = bx * 64;

  const __hip_bfloat16* Abase = A + (size_t)m0 * K;
  const __hip_bfloat16* Bbase = Bt + (size_t)n0 * K;
  const int NT = K >> 6;  // requires NT >= 3

  floatx4 acc[4][2];
#pragma unroll
  for (int r = 0; r < 4; ++r)
#pragma unroll
    for (int c = 0; c < 2; ++c) acc[r][c] = (floatx4){0.f, 0.f, 0.f, 0.f};

  short8 af[4][2], bf[2][2];

#define NB_RD(BUF)                                                             \
  do {                                                                         \
    _Pragma("unroll") for (int r = 0; r < 4; ++r) {                            \
      int row = wm + r * 16 + l15;                                             \
      _Pragma("unroll") for (int ks = 0; ks < 2; ++ks)                         \
          af[r][ks] = *reinterpret_cast<const short8*>(                        \
              &SA[BUF][row * 64 + (((ks * 4 + quad) ^ (l15 & 7)) * 8)]);       \
    }                                                                          \
    _Pragma("unroll") for (int c = 0; c < 2; ++c) {                            \
      int row = wn + c * 16 + l15;                                             \
      _Pragma("unroll") for (int ks = 0; ks < 2; ++ks)                         \
          bf[c][ks] = *reinterpret_cast<const short8*>(                        \
              &SB[BUF][row * 64 + (((ks * 4 + quad) ^ (l15 & 7)) * 8)]);       \
    }                                                                          \
  } while (0)
#define NB_MM                                                                  \
  do {                                                                         \
    _Pragma("unroll") for (int ks = 0; ks < 2; ++ks)                           \
        _Pragma("unroll") for (int r = 0; r < 4; ++r)                          \
            _Pragma("unroll") for (int c = 0; c < 2; ++c)                      \
                acc[r][c] = mfma_bf16(af[r][ks], bf[c][ks], acc[r][c]);        \
  } while (0)

  // ---- prologue: t0 -> buf0, t1 -> buf1 (per tile: A then B)
  stage_a128_t256(&SA[0][0], Abase, K, tid);
  stage_b64_t256(&SB[0][0], Bbase, K, tid);
  stage_a128_t256(&SA[1][0], Abase + 64, K, tid);
  stage_b64_t256(&SB[1][0], Bbase + 64, K, tid);
  VMW(6);  // forces tile 0 (A0,B0); tile 1's 6 loads stay in flight
  BAR;

  int cb = 0, sb = 2;
  for (int t = 0; t <= NT - 3; ++t) {
    const size_t k2 = (size_t)(t + 2) * 64;
    NB_RD(cb);
    stage_a128_t256(&SA[sb][0], Abase + k2, K, tid);
    stage_b64_t256(&SB[sb][0], Bbase + k2, K, tid);
    __builtin_amdgcn_s_setprio(1);
    NB_MM;
    __builtin_amdgcn_s_setprio(0);
    VMW(6);  // forces tile t+1 (issued phase t-1); tile t+2 stays in flight
    BAR;
    cb = (cb == 2) ? 0 : cb + 1;
    sb = (sb == 2) ? 0 : sb + 1;
  }
  {  // ---- t = NT-2: no stage, drain tile NT-1
    NB_RD(cb);
    __builtin_amdgcn_s_setprio(1);
    NB_MM;
    __builtin_amdgcn_s_setprio(0);
    VMW(0);
    BAR;
    cb = (cb == 2) ? 0 : cb + 1;
  }
  {  // ---- t = NT-1
    NB_RD(cb);
    __builtin_amdgcn_s_setprio(1);
    NB_MM;
    __builtin_amdgcn_s_setprio(0);
  }

  // ---- epilogue (fp32 out)
#pragma unroll
  for (int c = 0; c < 2; ++c) {
    int gn = n0 + wn + c * 16 + l15;
    float bv = bias[gn];
#pragma unroll
    for (int r = 0; r < 4; ++r)
#pragma unroll
      for (int rg = 0; rg < 4; ++rg) {
        int gm = m0 + wm + r * 16 + quad * 4 + rg;
        Cout[(size_t)gm * N + gn] = acc[r][c][rg] + bv;
      }
  }
#undef NB_RD
#undef NB_MM
}

// ---------------------------------------------------------------- flash attn v11
// v10 structure; launch_bounds (256,3) — part of the best measured config
// (167.6us, r7). VGPR headroom ~170 while keeping 3 blocks/CU.
__global__ __launch_bounds__(256, 3) void flash_attn(
    const __hip_bfloat16* __restrict__ qkv, __hip_bfloat16* __restrict__ out) {
  const int S = 2048, QKV = 3072;
  const int bx = blockIdx.x;
  const int g = (blockIdx.y >> 3) + 2 * blockIdx.z;
  int qt;
  if (g == 0)      qt = bx;
  else if (g == 1) qt = 31 - bx;
  else if (g == 2) qt = (bx + 8) & 31;
  else             qt = (23 - bx) & 31;
  const int h = blockIdx.y, b = blockIdx.z;
  const int q0 = qt * 64;
  __shared__ __align__(16) short Ps[2][64 * 64];  // P double-buffer; Ps[1] stages Q
  const int tid = threadIdx.x;
  const int wave = tid >> 6, lane = tid & 63, quad = lane >> 4, l15 = lane & 15;
  const int rx = l15 & 7;
  const __hip_bfloat16* base = qkv + (size_t)b * S * QKV;
  const float c2 = 0.18033688011112042f;  // (1/sqrt(64)) * log2(e)
  const floatx4 zero4 = {0.f, 0.f, 0.f, 0.f};
  const int krow = 16 * wave + l15;  // wave's K-row (QK) and d-column (PV)

  const __hip_bfloat16* kbase = base + 1024 + h * 64;  // K plane
  const __hip_bfloat16* vbase = base + 2048 + h * 64;  // V plane

  // ---- prologue: Q (scaled) -> Ps[1]; K_0 frags -> regs
  for (int it = 0; it < 2; ++it) {
    int v = tid + it * 256;
    int row = v >> 3, cb = v & 7;
    int colp = (cb ^ (row & 7)) * 8;
    short8 qv = *reinterpret_cast<const short8*>(
        base + (size_t)(q0 + row) * QKV + h * 64 + cb * 8);
    short qs[8];
    for (int e = 0; e < 8; ++e) qs[e] = bf16s(sbf16(qv[e]) * c2);
    *reinterpret_cast<short8*>(&Ps[1][row * 64 + colp]) = *reinterpret_cast<short8*>(qs);
  }
  short8 kA0 = *reinterpret_cast<const short8*>(
      kbase + (size_t)krow * QKV + quad * 8);
  short8 kA1 = *reinterpret_cast<const short8*>(
      kbase + (size_t)krow * QKV + 32 + quad * 8);
  __syncthreads();  // Q visible

  short8 aq[4][2];  // Q B-frags: all 64 q rows x both d-halves
  for (int t4 = 0; t4 < 4; ++t4)
    for (int s = 0; s < 2; ++s)
      aq[t4][s] = *reinterpret_cast<const short8*>(
          &Ps[1][(t4 * 16 + l15) * 64 + (((s * 4 + quad) ^ rx) * 8)]);
  // (safe: Ps[1] is first overwritten as P in window j=1, after barrier_0)

  floatx4 o_acc[4];
  for (int m = 0; m < 4; ++m) o_acc[m] = zero4;
  float lsum4[4] = {0.f, 0.f, 0.f, 0.f};
  short8 vA0, vA1;  // V_{j-1} B-frags

  for (int j = 0; j <= qt; ++j) {
    const int cj = j & 1, pj = cj ^ 1;

    // ---- issue K_{j+1} A-frags and V_j B-frags (consumed next window)
    short8 kB0, kB1, vB0, vB1;
    if (j < qt) {
      const __hip_bfloat16* kp = kbase + (size_t)((j + 1) * 64 + krow) * QKV;
      kB0 = *reinterpret_cast<const short8*>(kp + quad * 8);
      kB1 = *reinterpret_cast<const short8*>(kp + 32 + quad * 8);
    }
    {
      const __hip_bfloat16* vp = vbase + (size_t)(j * 64 + quad * 8) * QKV + krow;
      for (int i = 0; i < 8; ++i) {
        vB0[i] = *reinterpret_cast<const short*>(vp + (size_t)i * QKV);
        vB1[i] = *reinterpret_cast<const short*>(vp + (size_t)(32 + i) * QKV);
      }
    }

    // ---- PV_{j-1}: all 64 q x wave's 16 d (P parity pj, V regs)
    if (j > 0) {
      for (int s = 0; s < 2; ++s) {
        short8 bv = s ? vA1 : vA0;
        for (int m = 0; m < 4; ++m) {
          short8 ap = *reinterpret_cast<const short8*>(
              &Ps[pj][(m * 16 + l15) * 64 + (((4 * s + quad) ^ rx) * 8)]);
          o_acc[m] = mfma_bf16(ap, bv, o_acc[m]);
        }
      }
    }

    // ---- QK_j: wave's 16 k-rows x all 64 q (K regs)
    floatx4 sc[4];
    for (int t4 = 0; t4 < 4; ++t4) {
      sc[t4] = mfma_bf16(kA0, aq[t4][0], zero4);
      sc[t4] = mfma_bf16(kA1, aq[t4][1], sc[t4]);
    }
    if (j == qt) {  // diagonal mask (local coords)
      int kloc = 16 * wave + quad * 4;
      for (int t4 = 0; t4 < 4; ++t4)
        for (int rg = 0; rg < 4; ++rg)
          if (kloc + rg > t4 * 16 + l15) sc[t4][rg] = -1e30f;
    }

    // ---- exp2 (m=0) + P-write_j (parity cj)
    const int pcol = ((2 * wave + (quad >> 1)) ^ rx) * 8 + (quad & 1) * 4;
    for (int t4 = 0; t4 < 4; ++t4) {
      short pp[4];
      for (int rg = 0; rg < 4; ++rg) {
        float p = exp2_fast(sc[t4][rg]);
        lsum4[t4] += p;
        pp[rg] = bf16s(p);
      }
      *reinterpret_cast<s4v*>(&Ps[cj][(t4 * 16 + l15) * 64 + pcol]) =
          *reinterpret_cast<s4v*>(pp);
    }

    kA0 = kB0; kA1 = kB1; vA0 = vB0; vA1 = vB1;
    __syncthreads();  // single barrier: P_j visible, PV_{j-1} reads done
  }

  // ---- epilogue: PV_qt (V_qt regs, P parity qt&1)
  const int pq = qt & 1;
  for (int s = 0; s < 2; ++s) {
    short8 bv = s ? vA1 : vA0;
    for (int m = 0; m < 4; ++m) {
      short8 ap = *reinterpret_cast<const short8*>(
          &Ps[pq][(m * 16 + l15) * 64 + (((4 * s + quad) ^ rx) * 8)]);
      o_acc[m] = mfma_bf16(ap, bv, o_acc[m]);
    }
  }
  // lsum merge (additive, m=0): quad-reduce then LDS table in the other buffer
  for (int t4 = 0; t4 < 4; ++t4) {
    lsum4[t4] += __shfl_xor(lsum4[t4], 16);
    lsum4[t4] += __shfl_xor(lsum4[t4], 32);
  }
  float* Lf = (float*)&Ps[pq ^ 1][0];  // disjoint from PV_qt reads
  if (quad == 0)
    for (int t4 = 0; t4 < 4; ++t4)
      Lf[wave * 64 + t4 * 16 + l15] = lsum4[t4];
  __syncthreads();
  if (tid < 64)
    Lf[256 + tid] = 1.0f / (Lf[tid] + Lf[64 + tid] + Lf[128 + tid] + Lf[192 + tid]);
  __syncthreads();

  const int dcol = h * 64 + krow;
  for (int m = 0; m < 4; ++m)
    for (int rg = 0; rg < 4; ++rg) {
      int q = m * 16 + quad * 4 + rg;
      out[(size_t)(b * S + q0 + q) * 1024 + dcol] =
          __float2bfloat16(o_acc[m][rg] * Lf[256 + q]);
    }
}

// ---------------------------------------------------------------- launch
extern "C" void kernel_launch(void* const* d_in, const int* in_sizes, int n_in,
                              void* d_out, int out_size, void* d_ws, size_t ws_size,
                              hipStream_t stream) {
  const float* x    = (const float*)d_in[0];
  const float* Wqkv = (const float*)d_in[1];
  const float* bqkv = (const float*)d_in[2];
  const float* Wout = (const float*)d_in[3];
  const float* bout = (const float*)d_in[4];
  float* out = (float*)d_out;

  const int BS = 2 * 2048;
  const int D = 1024;
  char* ws = (char*)d_ws;
  __hip_bfloat16* xb    = (__hip_bfloat16*)(ws);
  __hip_bfloat16* wqkvb = (__hip_bfloat16*)(ws + (size_t)8  * 1048576);
  __hip_bfloat16* wob   = (__hip_bfloat16*)(ws + (size_t)14 * 1048576);
  __hip_bfloat16* qkvb  = (__hip_bfloat16*)(ws + (size_t)16 * 1048576);
  __hip_bfloat16* attnb = (__hip_bfloat16*)(ws + (size_t)40 * 1048576);

  cvt_all<<<4096, 256, 0, stream>>>(x, Wqkv, Wout, xb, wqkvb, wob);

  gemm_256<true><<<dim3(3072 / 256, BS / 256), 512, 0, stream>>>(
      xb, wqkvb, bqkv, qkvb, BS, 3 * D, D);

  flash_attn<<<dim3(32, 16, 2), 256, 0, stream>>>(qkvb, attnb);

  gemm_n64b<<<dim3(1024 / 64, BS / 128), 256, 0, stream>>>(
      attnb, wob, bout, out, BS, D, D);
}

// Round 12
// 163.908 us; speedup vs baseline: 1.3826x; 1.0086x over previous
//
#include <hip/hip_runtime.h>
#include <hip/hip_bf16.h>

typedef __attribute__((ext_vector_type(8))) short short8;
typedef __attribute__((ext_vector_type(4))) short s4v;
typedef __attribute__((ext_vector_type(4))) float floatx4;

__device__ inline floatx4 mfma_bf16(short8 a, short8 b, floatx4 c) {
  return __builtin_amdgcn_mfma_f32_16x16x32_bf16(a, b, c, 0, 0, 0);
}
__device__ inline float exp2_fast(float x) { return __builtin_amdgcn_exp2f(x); }

__device__ inline short bf16s(float f) {
  __hip_bfloat16 h = __float2bfloat16(f);
  return *reinterpret_cast<short*>(&h);
}
__device__ inline float sbf16(short s) {
  return __bfloat162float(*reinterpret_cast<__hip_bfloat16*>(&s));
}

// async global->LDS, 16B per lane. LDS dest must be wave-uniform base + lane*16.
__device__ inline void gld16(__hip_bfloat16* lds, const __hip_bfloat16* g) {
  __builtin_amdgcn_global_load_lds(
      (const __attribute__((address_space(1))) void*)g,
      (__attribute__((address_space(3))) void*)lds, 16, 0, 0);
}

// ---------------------------------------------------------------- fused cvt
__global__ __launch_bounds__(256) void cvt_all(
    const float* __restrict__ x, const float* __restrict__ wqkv,
    const float* __restrict__ wout, __hip_bfloat16* __restrict__ xb,
    __hip_bfloat16* __restrict__ wqkvb, __hip_bfloat16* __restrict__ wob) {
  const int n1 = 4194304, n2 = 3145728;  // n3 = 1048576
  int i = (blockIdx.x * 256 + threadIdx.x) * 8;
  const float* src;
  __hip_bfloat16* dst;
  int off;
  if (i < n1) { src = x; dst = xb; off = i; }
  else if (i < n1 + n2) { src = wqkv; dst = wqkvb; off = i - n1; }
  else { src = wout; dst = wob; off = i - n1 - n2; }
  float4 a = *reinterpret_cast<const float4*>(src + off);
  float4 b = *reinterpret_cast<const float4*>(src + off + 4);
  __hip_bfloat16 t[8];
  t[0] = __float2bfloat16(a.x); t[1] = __float2bfloat16(a.y);
  t[2] = __float2bfloat16(a.z); t[3] = __float2bfloat16(a.w);
  t[4] = __float2bfloat16(b.x); t[5] = __float2bfloat16(b.y);
  t[6] = __float2bfloat16(b.z); t[7] = __float2bfloat16(b.w);
  *reinterpret_cast<short8*>(dst + off) = *reinterpret_cast<short8*>(t);
}

// ================================================================ shared GEMM bits
__device__ inline void stage_half(__hip_bfloat16* lds, const __hip_bfloat16* g,
                                  int K, int tid) {
#pragma unroll
  for (int it = 0; it < 2; ++it) {
    int idx = it * 512 + tid;
    int row = idx >> 3, col = ((idx & 7) ^ (row & 7)) * 8;
    gld16(lds + idx * 8, g + (size_t)row * K + col);
  }
}
// 256-thread variants: A tile 128x64 (16KB, 4 iters), B tile 64x64 (8KB, 2 iters)
__device__ inline void stage_a128_t256(__hip_bfloat16* lds, const __hip_bfloat16* g,
                                       int K, int tid) {
#pragma unroll
  for (int it = 0; it < 4; ++it) {
    int idx = it * 256 + tid;
    int row = idx >> 3, col = ((idx & 7) ^ (row & 7)) * 8;
    gld16(lds + idx * 8, g + (size_t)row * K + col);
  }
}
__device__ inline void stage_b64_t256(__hip_bfloat16* lds, const __hip_bfloat16* g,
                                      int K, int tid) {
#pragma unroll
  for (int it = 0; it < 2; ++it) {
    int idx = it * 256 + tid;
    int row = idx >> 3, col = ((idx & 7) ^ (row & 7)) * 8;
    gld16(lds + idx * 8, g + (size_t)row * K + col);
  }
}

#define VMW(N) asm volatile("s_waitcnt vmcnt(" #N ")" ::: "memory")
#define BAR __builtin_amdgcn_s_barrier()

// ---------------------------------------------------------------- GEMM 256x256 v5 (QKV)
// v4 read-once schedule, SINGLE barrier per phase. Every ds_read is consumed
// by its own phase's MFMA (compiler lgkmcnt's before first use), so a wave's
// reads of buffer cb complete before it reaches the end-of-phase barrier;
// every stage into cb is issued after that barrier -> no DMA-vs-read race.
// Phase = RD; STG; MFMA; WT; BAR.
// Phase order (0,0),(1,0),(1,1),(0,1); stages P1:A0+B0(t+2), P2:A1, P3:B1;
// waits end-P0 vmcnt(10), end-P1 vmcnt(12), end-P3 vmcnt(12) (6-7 ph slack).
// [Register-feasibility, established r3/r9: gfx950 unified VGPR/AGPR file:
// acc(128 AGPR) + 2 waves/SIMD -> 128 arch-VGPR cap; only this in-phase
// schedule fits. Read-ahead ping-pong spills (r9: WRITE_SIZE 158MB, 94us).]
#define LDA8(dst, BUF, MH)                                                     \
  do {                                                                         \
    _Pragma("unroll") for (int mf = 0; mf < 4; ++mf) {                         \
      int rh = wm * 64 + mf * 16 + l15;                                        \
      _Pragma("unroll") for (int ks = 0; ks < 2; ++ks)                         \
          dst[mf][ks] = *reinterpret_cast<const short8*>(                      \
              &SA[BUF][MH][rh * 64 + (((ks * 4 + quad) ^ (rh & 7)) * 8)]);     \
    }                                                                          \
  } while (0)
#define LDB4(dst, BUF, NH)                                                     \
  do {                                                                         \
    _Pragma("unroll") for (int nf = 0; nf < 2; ++nf) {                         \
      int rh = wn * 32 + nf * 16 + l15;                                        \
      _Pragma("unroll") for (int ks = 0; ks < 2; ++ks)                         \
          dst[nf][ks] = *reinterpret_cast<const short8*>(                      \
              &SB[BUF][NH][rh * 64 + (((ks * 4 + quad) ^ (rh & 7)) * 8)]);     \
    }                                                                          \
  } while (0)
#define MM16(MH, NH, AF, BF)                                                   \
  do {                                                                         \
    _Pragma("unroll") for (int mf = 0; mf < 4; ++mf)                           \
        _Pragma("unroll") for (int nf = 0; nf < 2; ++nf) {                     \
      acc[MH][NH][mf][nf] = mfma_bf16(AF[mf][0], BF[nf][0], acc[MH][NH][mf][nf]); \
      acc[MH][NH][mf][nf] = mfma_bf16(AF[mf][1], BF[nf][1], acc[MH][NH][mf][nf]); \
    }                                                                          \
  } while (0)
#define PH(RD, STG, MH, NH, AF, BF, WT)                                        \
  do {                                                                         \
    RD;                                                                        \
    STG;                                                                       \
    __builtin_amdgcn_s_setprio(1);                                             \
    MM16(MH, NH, AF, BF);                                                      \
    __builtin_amdgcn_s_setprio(0);                                             \
    WT;                                                                        \
    BAR;                                                                       \
  } while (0)

template<bool OUT_BF16>
__global__ __launch_bounds__(512, 2) void gemm_256(
    const __hip_bfloat16* __restrict__ A, const __hip_bfloat16* __restrict__ Bt,
    const float* __restrict__ bias, void* __restrict__ Cout,
    int M, int N, int K) {
  __shared__ __align__(16) __hip_bfloat16 SA[2][2][128 * 64];
  __shared__ __align__(16) __hip_bfloat16 SB[2][2][128 * 64];
  const int tid = threadIdx.x;
  const int lane = tid & 63, quad = (lane >> 4), l15 = lane & 15;
  const int wave = tid >> 6;
  const int wm = wave >> 2, wn = wave & 3;

  // bijective XCD swizzle (nwg % 8 == 0 for our shapes)
  const int nbx = gridDim.x;
  int bid = blockIdx.y * nbx + blockIdx.x;
  const int nwg = nbx * gridDim.y;
  if ((nwg & 7) == 0) bid = (bid & 7) * (nwg >> 3) + (bid >> 3);
  const int bx = bid % nbx, by = bid / nbx;
  const int m0 = by * 256, n0 = bx * 256;

  const __hip_bfloat16* Abase = A + (size_t)m0 * K;
  const __hip_bfloat16* Bbase = Bt + (size_t)n0 * K;
  const int NT = K >> 6;  // requires NT >= 3

  floatx4 acc[2][2][4][2];
#pragma unroll
  for (int a = 0; a < 2; ++a)
#pragma unroll
    for (int b = 0; b < 2; ++b)
#pragma unroll
      for (int c = 0; c < 4; ++c)
#pragma unroll
        for (int d = 0; d < 2; ++d) acc[a][b][c][d] = (floatx4){0.f, 0.f, 0.f, 0.f};

  short8 af0[4][2], af1[4][2];  // A frags mh0 (live P0-P3), mh1 (live P1-P2)
  short8 bf0[2][2], bf1[2][2];  // B frags nh0 (live P0-P1), nh1 (live P2-P3)

  // ---- prologue: tiles 0,1 in steady issue order {A0,B0,A1,B1}
  stage_half(&SA[0][0][0], Abase, K, tid);
  stage_half(&SB[0][0][0], Bbase, K, tid);
  stage_half(&SA[0][1][0], Abase + (size_t)128 * K, K, tid);
  stage_half(&SB[0][1][0], Bbase + (size_t)128 * K, K, tid);
  stage_half(&SA[1][0][0], Abase + 64, K, tid);
  stage_half(&SB[1][0][0], Bbase + 64, K, tid);
  stage_half(&SA[1][1][0], Abase + (size_t)128 * K + 64, K, tid);
  stage_half(&SB[1][1][0], Bbase + (size_t)128 * K + 64, K, tid);
  VMW(12);  // forces A0(0),B0(0)
  BAR;

  // ---- steady: t in [0, NT-3], stage tile t+2 into buffer cb
  for (int t = 0; t <= NT - 3; ++t) {
    const int cb = t & 1;
    const size_t k2 = (size_t)(t + 2) * 64;
    PH({ LDA8(af0, cb, 0); LDB4(bf0, cb, 0); }, (void)0,
       0, 0, af0, bf0, VMW(10));
    PH(LDA8(af1, cb, 1),
       { stage_half(&SA[cb][0][0], Abase + k2, K, tid);
         stage_half(&SB[cb][0][0], Bbase + k2, K, tid); },
       1, 0, af1, bf0, VMW(12));
    PH(LDB4(bf1, cb, 1),
       stage_half(&SA[cb][1][0], Abase + (size_t)128 * K + k2, K, tid),
       1, 1, af1, bf1, (void)0);
    PH((void)0,
       stage_half(&SB[cb][1][0], Bbase + (size_t)128 * K + k2, K, tid),
       0, 1, af0, bf1, VMW(12));
  }
  {  // ---- t = NT-2: no stages, draining waits
    const int cb = (NT - 2) & 1;
    PH({ LDA8(af0, cb, 0); LDB4(bf0, cb, 0); }, (void)0, 0, 0, af0, bf0, VMW(10));
    PH(LDA8(af1, cb, 1), (void)0, 1, 0, af1, bf0, VMW(8));
    PH(LDB4(bf1, cb, 1), (void)0, 1, 1, af1, bf1, (void)0);
    PH((void)0, (void)0, 0, 1, af0, bf1, VMW(4));
  }
  {  // ---- t = NT-1: final tile
    const int cb = (NT - 1) & 1;
    PH({ LDA8(af0, cb, 0); LDB4(bf0, cb, 0); }, (void)0, 0, 0, af0, bf0, VMW(2));
    PH(LDA8(af1, cb, 1), (void)0, 1, 0, af1, bf0, VMW(0));
    LDB4(bf1, cb, 1);
    __builtin_amdgcn_s_setprio(1);
    MM16(1, 1, af1, bf1);
    MM16(0, 1, af0, bf1);
    __builtin_amdgcn_s_setprio(0);
  }

  // ---- epilogue
#pragma unroll
  for (int nh = 0; nh < 2; ++nh)
#pragma unroll
    for (int nf = 0; nf < 2; ++nf) {
      int gn = n0 + nh * 128 + wn * 32 + nf * 16 + l15;
      float bv = bias[gn];
#pragma unroll
      for (int mh = 0; mh < 2; ++mh)
#pragma unroll
        for (int mf = 0; mf < 4; ++mf)
#pragma unroll
          for (int rg = 0; rg < 4; ++rg) {
            int gm = m0 + mh * 128 + wm * 64 + mf * 16 + quad * 4 + rg;
            float v = acc[mh][nh][mf][nf][rg] + bv;
            if (OUT_BF16)
              ((__hip_bfloat16*)Cout)[(size_t)gm * N + gn] = __float2bfloat16(v);
            else
              ((float*)Cout)[(size_t)gm * N + gn] = v;
          }
    }
}

// ---------------------------------------------------------------- GEMM 128x64 (out-proj) v4
// TLP variant: gemm_bt<64> geometry (indices r0-verified) + v3 triple-buffer
// pipeline. 256 thr = 4 waves (2M x 2N), per-wave 64x32 out (acc 32 AGPR).
// LDS: 3 x (A 16KB + B 8KB) = 72KB -> 2 blocks/CU; grid (16,32)=512 = 2/CU.
// Phase t: read A,B from buf cb=t%3 (12 ds_read, consumed in-phase);
//   stage tile t+2 -> buf (t+2)%3 (slot's last read = phase t-1, sealed by
//   its end barrier -> no DMA race); 16 MFMA; VMW(6) forces tile t+1
//   (12 outstanding: 6 of t+1 issued @t-1 + 6 of t+2 issued @t); BAR.
// Prologue: stage t0,t1 (12 loads), VMW(6) forces t0. Tails: NT-2 -> VMW(0);
// NT-1 -> none. Requires NT >= 3. [r11: -3.4us vs 1-block/CU v3]
__global__ __launch_bounds__(256, 2) void gemm_n64b(
    const __hip_bfloat16* __restrict__ A, const __hip_bfloat16* __restrict__ Bt,
    const float* __restrict__ bias, float* __restrict__ Cout,
    int M, int N, int K) {
  __shared__ __align__(16) __hip_bfloat16 SA[3][128 * 64];
  __shared__ __align__(16) __hip_bfloat16 SB[3][64 * 64];
  const int tid = threadIdx.x;
  const int wave = tid >> 6, lane = tid & 63, quad = lane >> 4, l15 = lane & 15;
  const int wm = (wave >> 1) * 64, wn = (wave & 1) * 32;

  const int nbx = gridDim.x;
  int bid = blockIdx.y * nbx + blockIdx.x;
  const int nwg = nbx * gridDim.y;
  if ((nwg & 7) == 0) bid = (bid & 7) * (nwg >> 3) + (bid >> 3);
  const int bx = bid % nbx, by = bid / nbx;
  const int m0 = by * 128, n0 = bx * 64;

  const __hip_bfloat16* Abase = A + (size_t)m0 * K;
  const __hip_bfloat16* Bbase = Bt + (size_t)n0 * K;
  const int NT = K >> 6;  // requires NT >= 3

  floatx4 acc[4][2];
#pragma unroll
  for (int r = 0; r < 4; ++r)
#pragma unroll
    for (int c = 0; c < 2; ++c) acc[r][c] = (floatx4){0.f, 0.f, 0.f, 0.f};

  short8 af[4][2], bf[2][2];

#define NB_RD(BUF)                                                             \
  do {                                                                         \
    _Pragma("unroll") for (int r = 0; r < 4; ++r) {                            \
      int row = wm + r * 16 + l15;                                             \
      _Pragma("unroll") for (int ks = 0; ks < 2; ++ks)                         \
          af[r][ks] = *reinterpret_cast<const short8*>(                        \
              &SA[BUF][row * 64 + (((ks * 4 + quad) ^ (l15 & 7)) * 8)]);       \
    }                                                                          \
    _Pragma("unroll") for (int c = 0; c < 2; ++c) {                            \
      int row = wn + c * 16 + l15;                                             \
      _Pragma("unroll") for (int ks = 0; ks < 2; ++ks)                         \
          bf[c][ks] = *reinterpret_cast<const short8*>(                        \
              &SB[BUF][row * 64 + (((ks * 4 + quad) ^ (l15 & 7)) * 8)]);       \
    }                                                                          \
  } while (0)
#define NB_MM                                                                  \
  do {                                                                         \
    _Pragma("unroll") for (int ks = 0; ks < 2; ++ks)                           \
        _Pragma("unroll") for (int r = 0; r < 4; ++r)                          \
            _Pragma("unroll") for (int c = 0; c < 2; ++c)                      \
                acc[r][c] = mfma_bf16(af[r][ks], bf[c][ks], acc[r][c]);        \
  } while (0)

  // ---- prologue: t0 -> buf0, t1 -> buf1 (per tile: A then B)
  stage_a128_t256(&SA[0][0], Abase, K, tid);
  stage_b64_t256(&SB[0][0], Bbase, K, tid);
  stage_a128_t256(&SA[1][0], Abase + 64, K, tid);
  stage_b64_t256(&SB[1][0], Bbase + 64, K, tid);
  VMW(6);  // forces tile 0 (A0,B0); tile 1's 6 loads stay in flight
  BAR;

  int cb = 0, sb = 2;
  for (int t = 0; t <= NT - 3; ++t) {
    const size_t k2 = (size_t)(t + 2) * 64;
    NB_RD(cb);
    stage_a128_t256(&SA[sb][0], Abase + k2, K, tid);
    stage_b64_t256(&SB[sb][0], Bbase + k2, K, tid);
    __builtin_amdgcn_s_setprio(1);
    NB_MM;
    __builtin_amdgcn_s_setprio(0);
    VMW(6);  // forces tile t+1 (issued phase t-1); tile t+2 stays in flight
    BAR;
    cb = (cb == 2) ? 0 : cb + 1;
    sb = (sb == 2) ? 0 : sb + 1;
  }
  {  // ---- t = NT-2: no stage, drain tile NT-1
    NB_RD(cb);
    __builtin_amdgcn_s_setprio(1);
    NB_MM;
    __builtin_amdgcn_s_setprio(0);
    VMW(0);
    BAR;
    cb = (cb == 2) ? 0 : cb + 1;
  }
  {  // ---- t = NT-1
    NB_RD(cb);
    __builtin_amdgcn_s_setprio(1);
    NB_MM;
    __builtin_amdgcn_s_setprio(0);
  }

  // ---- epilogue (fp32 out)
#pragma unroll
  for (int c = 0; c < 2; ++c) {
    int gn = n0 + wn + c * 16 + l15;
    float bv = bias[gn];
#pragma unroll
    for (int r = 0; r < 4; ++r)
#pragma unroll
      for (int rg = 0; rg < 4; ++rg) {
        int gm = m0 + wm + r * 16 + quad * 4 + rg;
        Cout[(size_t)gm * N + gn] = acc[r][c][rg] + bv;
      }
  }
#undef NB_RD
#undef NB_MM
}

// ---------------------------------------------------------------- flash attn v12
// v10 structure; launch_bounds (256,4): grid 1024 = exactly 4 blocks/CU, so
// 4-block residency maximizes TLP if VGPR fits the 128 cap (r7 measured
// 167.6 with this vs r10's 168.7 at (256,3) on otherwise-identical code).
__global__ __launch_bounds__(256, 4) void flash_attn(
    const __hip_bfloat16* __restrict__ qkv, __hip_bfloat16* __restrict__ out) {
  const int S = 2048, QKV = 3072;
  const int bx = blockIdx.x;
  const int g = (blockIdx.y >> 3) + 2 * blockIdx.z;
  int qt;
  if (g == 0)      qt = bx;
  else if (g == 1) qt = 31 - bx;
  else if (g == 2) qt = (bx + 8) & 31;
  else             qt = (23 - bx) & 31;
  const int h = blockIdx.y, b = blockIdx.z;
  const int q0 = qt * 64;
  __shared__ __align__(16) short Ps[2][64 * 64];  // P double-buffer; Ps[1] stages Q
  const int tid = threadIdx.x;
  const int wave = tid >> 6, lane = tid & 63, quad = lane >> 4, l15 = lane & 15;
  const int rx = l15 & 7;
  const __hip_bfloat16* base = qkv + (size_t)b * S * QKV;
  const float c2 = 0.18033688011112042f;  // (1/sqrt(64)) * log2(e)
  const floatx4 zero4 = {0.f, 0.f, 0.f, 0.f};
  const int krow = 16 * wave + l15;  // wave's K-row (QK) and d-column (PV)

  const __hip_bfloat16* kbase = base + 1024 + h * 64;  // K plane
  const __hip_bfloat16* vbase = base + 2048 + h * 64;  // V plane

  // ---- prologue: Q (scaled) -> Ps[1]; K_0 frags -> regs
  for (int it = 0; it < 2; ++it) {
    int v = tid + it * 256;
    int row = v >> 3, cb = v & 7;
    int colp = (cb ^ (row & 7)) * 8;
    short8 qv = *reinterpret_cast<const short8*>(
        base + (size_t)(q0 + row) * QKV + h * 64 + cb * 8);
    short qs[8];
    for (int e = 0; e < 8; ++e) qs[e] = bf16s(sbf16(qv[e]) * c2);
    *reinterpret_cast<short8*>(&Ps[1][row * 64 + colp]) = *reinterpret_cast<short8*>(qs);
  }
  short8 kA0 = *reinterpret_cast<const short8*>(
      kbase + (size_t)krow * QKV + quad * 8);
  short8 kA1 = *reinterpret_cast<const short8*>(
      kbase + (size_t)krow * QKV + 32 + quad * 8);
  __syncthreads();  // Q visible

  short8 aq[4][2];  // Q B-frags: all 64 q rows x both d-halves
  for (int t4 = 0; t4 < 4; ++t4)
    for (int s = 0; s < 2; ++s)
      aq[t4][s] = *reinterpret_cast<const short8*>(
          &Ps[1][(t4 * 16 + l15) * 64 + (((s * 4 + quad) ^ rx) * 8)]);
  // (safe: Ps[1] is first overwritten as P in window j=1, after barrier_0)

  floatx4 o_acc[4];
  for (int m = 0; m < 4; ++m) o_acc[m] = zero4;
  float lsum4[4] = {0.f, 0.f, 0.f, 0.f};
  short8 vA0, vA1;  // V_{j-1} B-frags

  for (int j = 0; j <= qt; ++j) {
    const int cj = j & 1, pj = cj ^ 1;

    // ---- issue K_{j+1} A-frags and V_j B-frags (consumed next window)
    short8 kB0, kB1, vB0, vB1;
    if (j < qt) {
      const __hip_bfloat16* kp = kbase + (size_t)((j + 1) * 64 + krow) * QKV;
      kB0 = *reinterpret_cast<const short8*>(kp + quad * 8);
      kB1 = *reinterpret_cast<const short8*>(kp + 32 + quad * 8);
    }
    {
      const __hip_bfloat16* vp = vbase + (size_t)(j * 64 + quad * 8) * QKV + krow;
      for (int i = 0; i < 8; ++i) {
        vB0[i] = *reinterpret_cast<const short*>(vp + (size_t)i * QKV);
        vB1[i] = *reinterpret_cast<const short*>(vp + (size_t)(32 + i) * QKV);
      }
    }

    // ---- PV_{j-1}: all 64 q x wave's 16 d (P parity pj, V regs)
    if (j > 0) {
      for (int s = 0; s < 2; ++s) {
        short8 bv = s ? vA1 : vA0;
        for (int m = 0; m < 4; ++m) {
          short8 ap = *reinterpret_cast<const short8*>(
              &Ps[pj][(m * 16 + l15) * 64 + (((4 * s + quad) ^ rx) * 8)]);
          o_acc[m] = mfma_bf16(ap, bv, o_acc[m]);
        }
      }
    }

    // ---- QK_j: wave's 16 k-rows x all 64 q (K regs)
    floatx4 sc[4];
    for (int t4 = 0; t4 < 4; ++t4) {
      sc[t4] = mfma_bf16(kA0, aq[t4][0], zero4);
      sc[t4] = mfma_bf16(kA1, aq[t4][1], sc[t4]);
    }
    if (j == qt) {  // diagonal mask (local coords)
      int kloc = 16 * wave + quad * 4;
      for (int t4 = 0; t4 < 4; ++t4)
        for (int rg = 0; rg < 4; ++rg)
          if (kloc + rg > t4 * 16 + l15) sc[t4][rg] = -1e30f;
    }

    // ---- exp2 (m=0) + P-write_j (parity cj)
    const int pcol = ((2 * wave + (quad >> 1)) ^ rx) * 8 + (quad & 1) * 4;
    for (int t4 = 0; t4 < 4; ++t4) {
      short pp[4];
      for (int rg = 0; rg < 4; ++rg) {
        float p = exp2_fast(sc[t4][rg]);
        lsum4[t4] += p;
        pp[rg] = bf16s(p);
      }
      *reinterpret_cast<s4v*>(&Ps[cj][(t4 * 16 + l15) * 64 + pcol]) =
          *reinterpret_cast<s4v*>(pp);
    }

    kA0 = kB0; kA1 = kB1; vA0 = vB0; vA1 = vB1;
    __syncthreads();  // single barrier: P_j visible, PV_{j-1} reads done
  }

  // ---- epilogue: PV_qt (V_qt regs, P parity qt&1)
  const int pq = qt & 1;
  for (int s = 0; s < 2; ++s) {
    short8 bv = s ? vA1 : vA0;
    for (int m = 0; m < 4; ++m) {
      short8 ap = *reinterpret_cast<const short8*>(
          &Ps[pq][(m * 16 + l15) * 64 + (((4 * s + quad) ^ rx) * 8)]);
      o_acc[m] = mfma_bf16(ap, bv, o_acc[m]);
    }
  }
  // lsum merge (additive, m=0): quad-reduce then LDS table in the other buffer
  for (int t4 = 0; t4 < 4; ++t4) {
    lsum4[t4] += __shfl_xor(lsum4[t4], 16);
    lsum4[t4] += __shfl_xor(lsum4[t4], 32);
  }
  float* Lf = (float*)&Ps[pq ^ 1][0];  // disjoint from PV_qt reads
  if (quad == 0)
    for (int t4 = 0; t4 < 4; ++t4)
      Lf[wave * 64 + t4 * 16 + l15] = lsum4[t4];
  __syncthreads();
  if (tid < 64)
    Lf[256 + tid] = 1.0f / (Lf[tid] + Lf[64 + tid] + Lf[128 + tid] + Lf[192 + tid]);
  __syncthreads();

  const int dcol = h * 64 + krow;
  for (int m = 0; m < 4; ++m)
    for (int rg = 0; rg < 4; ++rg) {
      int q = m * 16 + quad * 4 + rg;
      out[(size_t)(b * S + q0 + q) * 1024 + dcol] =
          __float2bfloat16(o_acc[m][rg] * Lf[256 + q]);
    }
}

// ---------------------------------------------------------------- launch
extern "C" void kernel_launch(void* const* d_in, const int* in_sizes, int n_in,
                              void* d_out, int out_size, void* d_ws, size_t ws_size,
                              hipStream_t stream) {
  const float* x    = (const float*)d_in[0];
  const float* Wqkv = (const float*)d_in[1];
  const float* bqkv = (const float*)d_in[2];
  const float* Wout = (const float*)d_in[3];
  const float* bout = (const float*)d_in[4];
  float* out = (float*)d_out;

  const int BS = 2 * 2048;
  const int D = 1024;
  char* ws = (char*)d_ws;
  __hip_bfloat16* xb    = (__hip_bfloat16*)(ws);
  __hip_bfloat16* wqkvb = (__hip_bfloat16*)(ws + (size_t)8  * 1048576);
  __hip_bfloat16* wob   = (__hip_bfloat16*)(ws + (size_t)14 * 1048576);
  __hip_bfloat16* qkvb  = (__hip_bfloat16*)(ws + (size_t)16 * 1048576);
  __hip_bfloat16* attnb = (__hip_bfloat16*)(ws + (size_t)40 * 1048576);

  cvt_all<<<4096, 256, 0, stream>>>(x, Wqkv, Wout, xb, wqkvb, wob);

  gemm_256<true><<<dim3(3072 / 256, BS / 256), 512, 0, stream>>>(
      xb, wqkvb, bqkv, qkvb, BS, 3 * D, D);

  flash_attn<<<dim3(32, 16, 2), 256, 0, stream>>>(qkvb, attnb);

  gemm_n64b<<<dim3(1024 / 64, BS / 128), 256, 0, stream>>>(
      attnb, wob, bout, out, BS, D, D);
}